// Round 1
// baseline (5552.620 us; speedup 1.0000x reference)
//
#include <hip/hip_runtime.h>

typedef unsigned int u32;
typedef unsigned long long u64;

// ---------------- workspace layout (bytes) ----------------
#define WS_FEAT_A   0            // 2,097,152 f32 (8.39 MB)
#define WS_FEAT_B   8388608      // 2,097,152 f32
#define WS_XS0      16777216     // 49,152 f32
#define WS_XS1      16973824     // 49,152 f32
#define WS_FS       17170432     // 1,048,576 f32
#define WS_FPS      21364736     // 16,384 i32
#define WS_KNN      21430272     // 524,288 i32
#define WS_PMAX     23527424     // 8*8*1024 f32
#define WS_PSUM     23789568     // 8*8*1024 f64
#define WS_ACC      24313856     // zeroed per stage: acc_xk(64 dbl) acc_fk(64 dbl) acc_g(48 dbl)
#define WS_ACCI     24315392     // 48 dbl (init stats)
#define WS_PSTD     24315776     // 128 f32: [0..31] inv_std_xk, [32..63] inv_std_fk, [64] inv_ae, [65] blend
#define WS_PINIT    24316288     // 2 f32

__device__ __forceinline__ u64 shflx64(u64 v, int m) {
  return (u64)__shfl_xor((unsigned long long)v, m, 64);
}

// ---- strict (non-contracted) float math matching numpy op order ----
__device__ __forceinline__ float dist2_nc(float ax, float ay, float az,
                                          float bx, float by, float bz) {
#pragma clang fp contract(off)
  float dx = ax - bx, dy = ay - by, dz = az - bz;
  float d = dx * dx;
  d = d + dy * dy;
  d = d + dz * dz;
  return d;
}

__device__ __forceinline__ float sumsq3_nc(float x, float y, float z) {
#pragma clang fp contract(off)
  float d = x * x;
  d = d + y * y;
  d = d + z * z;
  return d;
}

__device__ __forceinline__ float knn_dist_nc(float qx, float qy, float qz, float qsq,
                                             float nx, float ny, float nz) {
#pragma clang fp contract(off)
  float dot = qx * nx;
  dot = dot + qy * ny;
  dot = dot + qz * nz;
  float nsq = nx * nx;
  nsq = nsq + ny * ny;
  nsq = nsq + nz * nz;
  float d = -2.0f * dot;
  d = d + qsq;
  d = d + nsq;
  return d;
}

// ================= FPS =================
// one block per batch; exact pointnet2 semantics (start at index 0)
template <int BLK, int P>
__global__ __launch_bounds__(BLK) void fps_kernel(const float* __restrict__ x,
                                                  int* __restrict__ out_idx, int S) {
  const int N = BLK * P;
  const int b = blockIdx.x;
  const float* xb = x + (size_t)b * N * 3;
  const int tid = threadIdx.x;
  const int lane = tid & 63;
  const int wid = tid >> 6;

  float px[P], py[P], pz[P], dist[P];
#pragma unroll
  for (int i = 0; i < P; ++i) {
    int idx = i * BLK + tid;
    px[i] = xb[idx * 3 + 0];
    py[i] = xb[idx * 3 + 1];
    pz[i] = xb[idx * 3 + 2];
    dist[i] = 1e10f;
  }

  __shared__ u64 warr[16];
  __shared__ u64 bestsh;
  int sel = 0;
  if (tid == 0) out_idx[b * S + 0] = 0;

#pragma unroll 1
  for (int it = 1; it < S; ++it) {
    float lx = xb[sel * 3 + 0];
    float ly = xb[sel * 3 + 1];
    float lz = xb[sel * 3 + 2];
    u64 key = 0;
#pragma unroll
    for (int i = 0; i < P; ++i) {
      float d = dist2_nc(px[i], py[i], pz[i], lx, ly, lz);
      float dm = fminf(dist[i], d);
      dist[i] = dm;
      u32 idx = (u32)(i * BLK + tid);
      u64 k = ((u64)__float_as_uint(dm) << 32) | (u64)(0xFFFFFFFFu - idx);
      key = (key > k) ? key : k;  // max dist, tie -> min idx
    }
#pragma unroll
    for (int m = 1; m < 64; m <<= 1) {
      u64 o = shflx64(key, m);
      key = (key > o) ? key : o;
    }
    if (lane == 0) warr[wid] = key;
    __syncthreads();
    if (wid == 0) {
      constexpr int NW = BLK / 64;
      u64 k2 = (lane < NW) ? warr[lane] : 0ull;
#pragma unroll
      for (int m = 1; m < 64; m <<= 1) {
        u64 o = shflx64(k2, m);
        k2 = (k2 > o) ? k2 : o;
      }
      if (lane == 0) {
        bestsh = k2;
        out_idx[b * S + it] = (int)(0xFFFFFFFFu - (u32)k2);
      }
    }
    __syncthreads();
    sel = (int)(0xFFFFFFFFu - (u32)bestsh);
  }
}

// ================= gathers =================
__global__ __launch_bounds__(256) void gather_xs_kernel(const float* __restrict__ x,
                                                        const int* __restrict__ fidx,
                                                        float* __restrict__ xs, int S, int N) {
  int t = blockIdx.x * 256 + threadIdx.x;
  if (t >= 8 * S * 3) return;
  int c = t % 3;
  int q = t / 3;
  int b = q / S;
  xs[t] = x[((size_t)b * N + fidx[q]) * 3 + c];
}

__global__ __launch_bounds__(256) void gather_fs_kernel(const float* __restrict__ feat,
                                                        const int* __restrict__ fidx,
                                                        float* __restrict__ fs, int S, int N, int C) {
  int t = blockIdx.x * 256 + threadIdx.x;
  if (t >= 8 * S * C) return;
  int c = t & (C - 1);
  int q = t / C;
  int b = q / S;
  fs[t] = feat[((size_t)b * N + fidx[q]) * C + c];
}

// ================= kNN (wave per query, u64-key stable selection sort) =================
template <int P>  // N = 64*P candidates
__global__ __launch_bounds__(256) void knn_kernel(const float* __restrict__ x,
                                                  const float* __restrict__ xs,
                                                  int* __restrict__ knn, int S) {
  constexpr int N = 64 * P;
  int wave = threadIdx.x >> 6, lane = threadIdx.x & 63;
  int q = blockIdx.x * 4 + wave;
  int b = q / S;
  const float* xb = x + (size_t)b * N * 3;
  float qx = xs[(size_t)q * 3 + 0];
  float qy = xs[(size_t)q * 3 + 1];
  float qz = xs[(size_t)q * 3 + 2];
  float qsq = sumsq3_nc(qx, qy, qz);

  u64 key[P];
#pragma unroll
  for (int i = 0; i < P; ++i) {
    int idx = i * 64 + lane;
    float nx = xb[idx * 3 + 0], ny = xb[idx * 3 + 1], nz = xb[idx * 3 + 2];
    float d = knn_dist_nc(qx, qy, qz, qsq, nx, ny, nz);
    u32 u = __float_as_uint(d);
    u32 msk = ((u32)(((int)u) >> 31)) | 0x80000000u;  // sortable float mapping (handles tiny negatives)
    u ^= msk;
    key[i] = ((u64)u << 32) | (u64)(u32)idx;
  }

  u64 prev = 0;
  u32 myv = 0;
#pragma unroll 1
  for (int r = 0; r < 32; ++r) {
    u64 best = ~0ull;
#pragma unroll
    for (int i = 0; i < P; ++i) {
      u64 k = key[i];
      u64 cand = (k > prev) ? k : ~0ull;
      best = (cand < best) ? cand : best;
    }
#pragma unroll
    for (int m = 1; m < 64; m <<= 1) {
      u64 o = shflx64(best, m);
      best = (o < best) ? o : best;
    }
    prev = best;
    if (lane == r) myv = (u32)best;
  }
  if (lane < 32) knn[(size_t)q * 32 + lane] = (int)myv;
}

// ================= per-k std stats (xk and fk) =================
template <int C>
__global__ __launch_bounds__(256) void stats1_kernel(const float* __restrict__ x,
                                                     const float* __restrict__ xs,
                                                     const float* __restrict__ feat,
                                                     const float* __restrict__ fs,
                                                     const int* __restrict__ knn,
                                                     double* __restrict__ acc_xk,
                                                     double* __restrict__ acc_fk, int S, int N) {
  int k = threadIdx.x & 31;
  int qs = threadIdx.x >> 5;  // 0..7
  int qbase = blockIdx.x * 32;
  double sx = 0, sxx = 0, sf = 0, sff = 0;
  for (int jj = 0; jj < 4; ++jj) {
    int q = qbase + qs * 4 + jj;
    int b = q / S;
    int nbr = knn[(size_t)q * 32 + k];
    const float* xr = x + ((size_t)b * N + nbr) * 3;
    const float* xq = xs + (size_t)q * 3;
#pragma unroll
    for (int c = 0; c < 3; ++c) {
      float d = xr[c] - xq[c];
      sx += (double)d;
      sxx += (double)d * (double)d;
    }
    const float4* fr = (const float4*)(feat + ((size_t)b * N + nbr) * C);
    const float4* fq = (const float4*)(fs + (size_t)q * C);
    for (int c = 0; c < C / 4; ++c) {
      float4 a = fr[c], bb = fq[c];
      float d0 = a.x - bb.x, d1 = a.y - bb.y, d2 = a.z - bb.z, d3 = a.w - bb.w;
      sf += (double)d0 + (double)d1 + (double)d2 + (double)d3;
      sff += (double)d0 * d0 + (double)d1 * d1 + (double)d2 * d2 + (double)d3 * d3;
    }
  }
  __shared__ double red[256];
  double vals[4] = {sx, sxx, sf, sff};
  double rr[4] = {0, 0, 0, 0};
#pragma unroll
  for (int p = 0; p < 4; ++p) {
    red[threadIdx.x] = vals[p];
    __syncthreads();
    if (threadIdx.x < 32) {
      double r = 0;
#pragma unroll
      for (int t = 0; t < 8; ++t) r += red[k + t * 32];
      rr[p] = r;
    }
    __syncthreads();
  }
  if (threadIdx.x < 32) {
    atomicAdd(&acc_xk[k * 2 + 0], rr[0]);
    atomicAdd(&acc_xk[k * 2 + 1], rr[1]);
    atomicAdd(&acc_fk[k * 2 + 0], rr[2]);
    atomicAdd(&acc_fk[k * 2 + 1], rr[3]);
  }
}

__global__ void finish_std(const double* __restrict__ acc_xk, const double* __restrict__ acc_fk,
                           float* __restrict__ pstd, int n1, int n2) {
  int k = threadIdx.x;
  if (k < 32) {
    double s = acc_xk[k * 2], ss = acc_xk[k * 2 + 1];
    double var = (ss - s * s / (double)n1) / (double)(n1 - 1);
    float st = (float)sqrt(var > 0.0 ? var : 0.0);
    st = fmaxf(st, 1e-5f);
    pstd[k] = 1.0f / st;
    s = acc_fk[k * 2];
    ss = acc_fk[k * 2 + 1];
    var = (ss - s * s / (double)n2) / (double)(n2 - 1);
    st = (float)sqrt(var > 0.0 ? var : 0.0);
    st = fmaxf(st, 1e-5f);
    pstd[32 + k] = 1.0f / st;
  }
}

// ================= gstd stats over normalized xk =================
__global__ __launch_bounds__(256) void stats2_kernel(const float* __restrict__ x,
                                                     const float* __restrict__ xs,
                                                     const int* __restrict__ knn,
                                                     const float* __restrict__ pstd,
                                                     double* __restrict__ acc_g, int S, int N) {
  int b = blockIdx.y;
  int total = S * 32;
  double a[3] = {0, 0, 0}, qq[3] = {0, 0, 0};
  for (int u = blockIdx.x * 256 + threadIdx.x; u < total; u += 32 * 256) {
    int s = u >> 5, k = u & 31;
    int nbr = knn[((size_t)b * S + s) * 32 + k];
    float is = pstd[k];
#pragma unroll
    for (int c = 0; c < 3; ++c) {
      float v = (x[((size_t)b * N + nbr) * 3 + c] - xs[((size_t)b * S + s) * 3 + c]) * is;
      a[c] += (double)v;
      qq[c] += (double)v * (double)v;
    }
  }
  __shared__ double red[256];
#pragma unroll
  for (int c = 0; c < 3; ++c) {
    red[threadIdx.x] = a[c];
    __syncthreads();
    for (int off = 128; off > 0; off >>= 1) {
      if (threadIdx.x < off) red[threadIdx.x] += red[threadIdx.x + off];
      __syncthreads();
    }
    if (threadIdx.x == 0) atomicAdd(&acc_g[(b * 3 + c) * 2], red[0]);
    __syncthreads();
    red[threadIdx.x] = qq[c];
    __syncthreads();
    for (int off = 128; off > 0; off >>= 1) {
      if (threadIdx.x < off) red[threadIdx.x] += red[threadIdx.x + off];
      __syncthreads();
    }
    if (threadIdx.x == 0) atomicAdd(&acc_g[(b * 3 + c) * 2 + 1], red[0]);
    __syncthreads();
  }
}

// gstd (24 slots of n samples each) -> params {inv(asig+eps), blend}
__global__ void finish_gstd(const double* __restrict__ acc, float* __restrict__ params, int n) {
  if (threadIdx.x == 0 && blockIdx.x == 0) {
    double g = 0;
    for (int i = 0; i < 24; ++i) {
      double s = acc[i * 2], ss = acc[i * 2 + 1];
      double var = (ss - s * s / (double)n) / (double)(n - 1);
      g += sqrt(var > 0.0 ? var : 0.0);
    }
    float gstd = (float)(g / 24.0);
    float asig = 0.26f * (1.0f + gstd);
    params[0] = 1.0f / (asig + 1e-6f);
    params[1] = 1.0f / (1.0f + expf(-(gstd - 0.1f) * 10.0f));
  }
}

// ================= init stats + init embed =================
__global__ __launch_bounds__(256) void init_stats(const float* __restrict__ xyz,
                                                  double* __restrict__ acc) {
  int bc = blockIdx.x;
  int b = bc / 3, c = bc - b * 3;
  double s = 0, ss = 0;
  for (int n = threadIdx.x; n < 4096; n += 256) {
    float v = xyz[((size_t)b * 4096 + n) * 3 + c];
    s += (double)v;
    ss += (double)v * (double)v;
  }
  __shared__ double r1[256], r2[256];
  r1[threadIdx.x] = s;
  r2[threadIdx.x] = ss;
  __syncthreads();
  for (int off = 128; off > 0; off >>= 1) {
    if (threadIdx.x < off) {
      r1[threadIdx.x] += r1[threadIdx.x + off];
      r2[threadIdx.x] += r2[threadIdx.x + off];
    }
    __syncthreads();
  }
  if (threadIdx.x == 0) {
    acc[bc * 2] = r1[0];
    acc[bc * 2 + 1] = r2[0];
  }
}

__global__ __launch_bounds__(256) void init_embed(const float* __restrict__ xyz,
                                                  const float* __restrict__ params,
                                                  float* __restrict__ feat) {
  int t = blockIdx.x * 256 + threadIdx.x;  // over 8*4096*64
  int j = t & 63;
  int n = (t >> 6) & 4095;
  int b = t >> 18;
  float inv_ae = params[0], blend = params[1];
  int idx = (int)((double)j * 65.0 / 63.0);
  int c = idx / 22, f = idx - c * 22;
  float fv = (float)(-1.0 + 2.0 * (double)(f + 1) / 23.0);
  float v = xyz[((size_t)b * 4096 + n) * 3 + c];
  float z = (v - fv) * inv_ae;
  float e = __expf(-0.5f * z * z);
  float co = __cosf(z);
  feat[t] = blend * e + (1.0f - blend) * co;
}

// ================= fused embed + gate + K-reduce + gelu =================
template <int C, int TWOC, int BLK, int FD>
__global__ __launch_bounds__(BLK) void fused_kernel(const float* __restrict__ x,
                                                    const float* __restrict__ xs,
                                                    const float* __restrict__ feat_in,
                                                    const float* __restrict__ fs,
                                                    const int* __restrict__ knn,
                                                    const float* __restrict__ pstd,
                                                    float* __restrict__ feat_out, int S, int N) {
  constexpr int JPT = TWOC / BLK;
  int q = blockIdx.x;
  int b = q / S;
  int tid = threadIdx.x;
  float inv_ae = pstd[64];
  float blend = pstd[65];
  float omb = 1.0f - blend;
  float c0 = xs[(size_t)q * 3 + 0];
  float c1 = xs[(size_t)q * 3 + 1];
  float c2 = xs[(size_t)q * 3 + 2];

  int cj[JPT];
  float fvj[JPT], fj[JPT], sum[JPT], mx[JPT];
#pragma unroll
  for (int i = 0; i < JPT; ++i) {
    int j = tid + i * BLK;
    int idx = (int)((double)j * (double)(3 * FD - 1) / (double)(TWOC - 1));
    int c = idx / FD, f = idx - c * FD;
    cj[i] = c;
    fvj[i] = (float)(-1.0 + 2.0 * (double)(f + 1) / (double)(FD + 1));
    fj[i] = fs[(size_t)q * C + (j < C ? j : j - C)];
    sum[i] = 0.0f;
    mx[i] = -3.4e38f;
  }

  const int* krow = knn + (size_t)q * 32;
#pragma unroll 1
  for (int k = 0; k < 32; ++k) {
    int nbr = krow[k];
    float isx = pstd[k], isf = pstd[32 + k];
    const float* xr = x + ((size_t)b * N + nbr) * 3;
    float xk0 = (xr[0] - c0) * isx;
    float xk1 = (xr[1] - c1) * isx;
    float xk2 = (xr[2] - c2) * isx;
    const float* fr = feat_in + ((size_t)b * N + nbr) * C;
#pragma unroll
    for (int i = 0; i < JPT; ++i) {
      int j = tid + i * BLK;
      float cat;
      if (j < C)
        cat = (fr[j] - fj[i]) * isf;
      else
        cat = fj[i];
      float xc = (cj[i] == 0) ? xk0 : ((cj[i] == 1) ? xk1 : xk2);
      float z = (xc - fvj[i]) * inv_ae;
      float comb = blend * __expf(-0.5f * z * z) + omb * __cosf(z);
      float fw = (cat + comb) * comb;
      sum[i] += fw;
      mx[i] = fmaxf(mx[i], fw);
    }
  }
#pragma unroll
  for (int i = 0; i < JPT; ++i) {
    float val = sum[i] * 0.03125f + mx[i];
    float g = 0.5f * val * (1.0f + erff(val * 0.7071067811865476f));
    feat_out[(size_t)q * TWOC + tid + i * BLK] = g;
  }
}

// ================= stage result reduce (max & mean over S) =================
template <int TWOC, int BLK>
__global__ __launch_bounds__(BLK) void result_partial(const float* __restrict__ feat,
                                                      float* __restrict__ pmax,
                                                      double* __restrict__ psum, int S) {
  int j = blockIdx.x * BLK + threadIdx.x;
  int ch = blockIdx.y, b = blockIdx.z;
  int rows = S >> 3;
  int s0 = ch * rows;
  float m = -3.4e38f;
  double sd = 0.0;
  for (int s = 0; s < rows; ++s) {
    float v = feat[((size_t)(b * S + s0 + s)) * TWOC + j];
    m = fmaxf(m, v);
    sd += (double)v;
  }
  pmax[((size_t)ch * 8 + b) * TWOC + j] = m;
  psum[((size_t)ch * 8 + b) * TWOC + j] = sd;
}

__global__ void result_final(const float* __restrict__ pmax, const double* __restrict__ psum,
                             float* __restrict__ out, int TWOC, int off, int S) {
  int t = blockIdx.x * 256 + threadIdx.x;
  if (t >= 8 * TWOC) return;
  int b = t / TWOC, j = t - b * TWOC;
  float m = -3.4e38f;
  double sd = 0.0;
  for (int ch = 0; ch < 8; ++ch) {
    m = fmaxf(m, pmax[((size_t)ch * 8 + b) * TWOC + j]);
    sd += psum[((size_t)ch * 8 + b) * TWOC + j];
  }
  out[(size_t)b * 3840 + off + j] = m;
  out[(size_t)b * 3840 + off + TWOC + j] = (float)(sd / (double)S);
}

// ================= stage driver =================
template <int N, int S, int C, int TWOC, int FD, int FBLK, int FP, int KP, int BLKF>
static void run_stage(const float* x, const float* feat_in, float* xs, float* fs, float* feat_out,
                      int* fps, int* knnb, double* accz, float* pstd, float* pmax, double* psum,
                      float* out, int outoff, hipStream_t stream) {
  static_assert(FBLK * FP == N, "fps size");
  static_assert(64 * KP == N, "knn size");
  double* acc_xk = accz;
  double* acc_fk = accz + 64;
  double* acc_g = accz + 128;

  fps_kernel<FBLK, FP><<<8, FBLK, 0, stream>>>(x, fps, S);
  gather_xs_kernel<<<(8 * S * 3 + 255) / 256, 256, 0, stream>>>(x, fps, xs, S, N);
  gather_fs_kernel<<<(8 * S * C) / 256, 256, 0, stream>>>(feat_in, fps, fs, S, N, C);
  knn_kernel<KP><<<(8 * S) / 4, 256, 0, stream>>>(x, xs, knnb, S);
  hipMemsetAsync(accz, 0, 1408, stream);
  stats1_kernel<C><<<(8 * S) / 32, 256, 0, stream>>>(x, xs, feat_in, fs, knnb, acc_xk, acc_fk, S, N);
  finish_std<<<1, 64, 0, stream>>>(acc_xk, acc_fk, pstd, 8 * S * 3, 8 * S * C);
  stats2_kernel<<<dim3(32, 8), 256, 0, stream>>>(x, xs, knnb, pstd, acc_g, S, N);
  finish_gstd<<<1, 64, 0, stream>>>(acc_g, pstd + 64, S * 32);
  fused_kernel<C, TWOC, BLKF, FD><<<8 * S, BLKF, 0, stream>>>(x, xs, feat_in, fs, knnb, pstd,
                                                              feat_out, S, N);
  constexpr int RBLK = (TWOC < 256) ? TWOC : 256;
  result_partial<TWOC, RBLK><<<dim3(TWOC / RBLK, 8, 8), RBLK, 0, stream>>>(feat_out, pmax, psum, S);
  result_final<<<(8 * TWOC + 255) / 256, 256, 0, stream>>>(pmax, psum, out, TWOC, outoff, S);
}

extern "C" void kernel_launch(void* const* d_in, const int* in_sizes, int n_in, void* d_out,
                              int out_size, void* d_ws, size_t ws_size, hipStream_t stream) {
  (void)in_sizes;
  (void)n_in;
  (void)out_size;
  (void)ws_size;
  const float* xyz = (const float*)d_in[0];
  float* out = (float*)d_out;
  char* w = (char*)d_ws;

  float* featA = (float*)(w + WS_FEAT_A);
  float* featB = (float*)(w + WS_FEAT_B);
  float* xs0 = (float*)(w + WS_XS0);
  float* xs1 = (float*)(w + WS_XS1);
  float* fs = (float*)(w + WS_FS);
  int* fps = (int*)(w + WS_FPS);
  int* knnb = (int*)(w + WS_KNN);
  float* pmax = (float*)(w + WS_PMAX);
  double* psum = (double*)(w + WS_PSUM);
  double* accz = (double*)(w + WS_ACC);
  double* acci = (double*)(w + WS_ACCI);
  float* pstd = (float*)(w + WS_PSTD);
  float* pinit = (float*)(w + WS_PINIT);

  // initial adaptive embed of xyz -> feat [8,4096,64]
  init_stats<<<24, 256, 0, stream>>>(xyz, acci);
  finish_gstd<<<1, 64, 0, stream>>>(acci, pinit, 4096);
  init_embed<<<(8 * 4096 * 64) / 256, 256, 0, stream>>>(xyz, pinit, featA);

  // 4 stages
  run_stage<4096, 2048, 64, 128, 43, 1024, 4, 64, 128>(xyz, featA, xs0, fs, featB, fps, knnb,
                                                       accz, pstd, pmax, psum, out, 0, stream);
  run_stage<2048, 1024, 128, 256, 86, 1024, 2, 32, 256>(xs0, featB, xs1, fs, featA, fps, knnb,
                                                        accz, pstd, pmax, psum, out, 256, stream);
  run_stage<1024, 512, 256, 512, 171, 1024, 1, 16, 256>(xs1, featA, xs0, fs, featB, fps, knnb,
                                                        accz, pstd, pmax, psum, out, 768, stream);
  run_stage<512, 256, 512, 1024, 342, 512, 1, 8, 256>(xs0, featB, xs1, fs, featA, fps, knnb,
                                                      accz, pstd, pmax, psum, out, 1792, stream);
}

// Round 2
// 4807.915 us; speedup vs baseline: 1.1549x; 1.1549x over previous
//
#include <hip/hip_runtime.h>

typedef unsigned int u32;
typedef unsigned long long u64;

// ---------------- workspace layout (bytes) ----------------
#define WS_FEAT_A   0            // 2,097,152 f32 (8.39 MB)
#define WS_FEAT_B   8388608      // 2,097,152 f32
#define WS_XS0      16777216     // 49,152 f32
#define WS_XS1      16973824     // 49,152 f32
#define WS_FS       17170432     // 1,048,576 f32
#define WS_FPS      21364736     // 16,384 i32
#define WS_KNN      21430272     // 524,288 i32
#define WS_PMAX     23527424     // 8*8*1024 f32
#define WS_PSUM     23789568     // 8*8*1024 f64
#define WS_ACC      24313856     // zeroed per stage: acc_xk(64 dbl) acc_fk(64 dbl) acc_g(48 dbl)
#define WS_ACCI     24315392     // 48 dbl (init stats)
#define WS_PSTD     24315776     // 128 f32: [0..31] inv_std_xk, [32..63] inv_std_fk, [64] inv_ae, [65] blend
#define WS_PINIT    24316288     // 2 f32

__device__ __forceinline__ u64 shflx64(u64 v, int m) {
  return (u64)__shfl_xor((unsigned long long)v, m, 64);
}

// ---- strict (non-contracted) float math matching numpy op order ----
__device__ __forceinline__ float dist2_nc(float ax, float ay, float az,
                                          float bx, float by, float bz) {
#pragma clang fp contract(off)
  float dx = ax - bx, dy = ay - by, dz = az - bz;
  float d = dx * dx;
  d = d + dy * dy;
  d = d + dz * dz;
  return d;
}

__device__ __forceinline__ float sumsq3_nc(float x, float y, float z) {
#pragma clang fp contract(off)
  float d = x * x;
  d = d + y * y;
  d = d + z * z;
  return d;
}

__device__ __forceinline__ float knn_dist_nc(float qx, float qy, float qz, float qsq,
                                             float nx, float ny, float nz) {
#pragma clang fp contract(off)
  float dot = qx * nx;
  dot = dot + qy * ny;
  dot = dot + qz * nz;
  float nsq = nx * nx;
  nsq = nsq + ny * ny;
  nsq = nsq + nz * nz;
  float d = -2.0f * dot;
  d = d + qsq;
  d = d + nsq;
  return d;
}

// ================= FPS =================
// one block per batch; exact pointnet2 semantics (start at index 0).
// Round structure (latency-optimized):
//   dist update -> thread-local argmax -> 6-step u64 butterfly (wave winner)
//   -> owner thread writes {key, coords} to parity LDS slot -> ONE barrier
//   -> every thread serially max-reduces NW wave keys (LDS broadcast reads)
//   -> coords of block winner read from LDS (no global re-load).
// Double-buffered slots remove the WAR hazard, so a single barrier per round
// is sufficient (writer of slot[p] at round it+2 must pass barrier(it+1),
// which readers of slot[p] at round it have already contributed to).
template <int BLK, int P>
__global__ __launch_bounds__(BLK) void fps_kernel(const float* __restrict__ x,
                                                  int* __restrict__ out_idx, int S) {
  constexpr int NW = BLK / 64;
  constexpr int LOG2BLK = __builtin_ctz(BLK);
  const int N = BLK * P;
  const int b = blockIdx.x;
  const float* xb = x + (size_t)b * N * 3;
  const int tid = threadIdx.x;
  const int wid = tid >> 6;

  float px[P], py[P], pz[P], dist[P];
  u32 inv[P];
#pragma unroll
  for (int i = 0; i < P; ++i) {
    int idx = i * BLK + tid;
    px[i] = xb[idx * 3 + 0];
    py[i] = xb[idx * 3 + 1];
    pz[i] = xb[idx * 3 + 2];
    dist[i] = 1e10f;
    inv[i] = 0xFFFFFFFFu - (u32)idx;
  }

  __shared__ u64 skey[2][NW];
  __shared__ float scoord[2][NW][3];

  if (tid == 0) out_idx[b * S + 0] = 0;
  float lx = xb[0], ly = xb[1], lz = xb[2];

#pragma unroll 1
  for (int it = 1; it < S; ++it) {
    const int p = it & 1;
    float bestd = -1.0f;
    u32 bestinv = 0;
#pragma unroll
    for (int i = 0; i < P; ++i) {
      float d = dist2_nc(px[i], py[i], pz[i], lx, ly, lz);
      float dm = fminf(dist[i], d);
      dist[i] = dm;
      if (dm > bestd) {  // strict > keeps smallest idx on ties (argmax first-occurrence)
        bestd = dm;
        bestinv = inv[i];
      }
    }
    u64 key = ((u64)__float_as_uint(bestd) << 32) | (u64)bestinv;
#pragma unroll
    for (int m = 1; m < 64; m <<= 1) {
      u64 o = shflx64(key, m);
      key = (key > o) ? key : o;
    }
    // wave winner's owner thread stashes key + coords (registers -> LDS)
    u32 widx = 0xFFFFFFFFu - (u32)key;
    if (tid == (int)(widx & (u32)(BLK - 1))) {
      int iw = (int)(widx >> LOG2BLK);
      float wx = 0.f, wy = 0.f, wz = 0.f;
#pragma unroll
      for (int i = 0; i < P; ++i) {
        if (i == iw) { wx = px[i]; wy = py[i]; wz = pz[i]; }
      }
      skey[p][wid] = key;
      scoord[p][wid][0] = wx;
      scoord[p][wid][1] = wy;
      scoord[p][wid][2] = wz;
    }
    __syncthreads();
    u64 bk = skey[p][0];
    int bw = 0;
#pragma unroll
    for (int w = 1; w < NW; ++w) {
      u64 kk = skey[p][w];
      if (kk > bk) { bk = kk; bw = w; }
    }
    lx = scoord[p][bw][0];
    ly = scoord[p][bw][1];
    lz = scoord[p][bw][2];
    if (tid == 0) out_idx[b * S + it] = (int)(0xFFFFFFFFu - (u32)bk);
  }
}

// ================= gathers =================
__global__ __launch_bounds__(256) void gather_xs_kernel(const float* __restrict__ x,
                                                        const int* __restrict__ fidx,
                                                        float* __restrict__ xs, int S, int N) {
  int t = blockIdx.x * 256 + threadIdx.x;
  if (t >= 8 * S * 3) return;
  int c = t % 3;
  int q = t / 3;
  int b = q / S;
  xs[t] = x[((size_t)b * N + fidx[q]) * 3 + c];
}

__global__ __launch_bounds__(256) void gather_fs_kernel(const float* __restrict__ feat,
                                                        const int* __restrict__ fidx,
                                                        float* __restrict__ fs, int S, int N, int C) {
  int t = blockIdx.x * 256 + threadIdx.x;
  if (t >= 8 * S * C) return;
  int c = t & (C - 1);
  int q = t / C;
  int b = q / S;
  fs[t] = feat[((size_t)b * N + fidx[q]) * C + c];
}

// ================= kNN (wave per query, u64-key stable selection sort) =================
template <int P>  // N = 64*P candidates
__global__ __launch_bounds__(256) void knn_kernel(const float* __restrict__ x,
                                                  const float* __restrict__ xs,
                                                  int* __restrict__ knn, int S) {
  constexpr int N = 64 * P;
  int wave = threadIdx.x >> 6, lane = threadIdx.x & 63;
  int q = blockIdx.x * 4 + wave;
  int b = q / S;
  const float* xb = x + (size_t)b * N * 3;
  float qx = xs[(size_t)q * 3 + 0];
  float qy = xs[(size_t)q * 3 + 1];
  float qz = xs[(size_t)q * 3 + 2];
  float qsq = sumsq3_nc(qx, qy, qz);

  u64 key[P];
#pragma unroll
  for (int i = 0; i < P; ++i) {
    int idx = i * 64 + lane;
    float nx = xb[idx * 3 + 0], ny = xb[idx * 3 + 1], nz = xb[idx * 3 + 2];
    float d = knn_dist_nc(qx, qy, qz, qsq, nx, ny, nz);
    u32 u = __float_as_uint(d);
    u32 msk = ((u32)(((int)u) >> 31)) | 0x80000000u;  // sortable float mapping (handles tiny negatives)
    u ^= msk;
    key[i] = ((u64)u << 32) | (u64)(u32)idx;
  }

  u64 prev = 0;
  u32 myv = 0;
#pragma unroll 1
  for (int r = 0; r < 32; ++r) {
    u64 best = ~0ull;
#pragma unroll
    for (int i = 0; i < P; ++i) {
      u64 k = key[i];
      u64 cand = (k > prev) ? k : ~0ull;
      best = (cand < best) ? cand : best;
    }
#pragma unroll
    for (int m = 1; m < 64; m <<= 1) {
      u64 o = shflx64(best, m);
      best = (o < best) ? o : best;
    }
    prev = best;
    if (lane == r) myv = (u32)best;
  }
  if (lane < 32) knn[(size_t)q * 32 + lane] = (int)myv;
}

// ================= per-k std stats (xk and fk) =================
template <int C>
__global__ __launch_bounds__(256) void stats1_kernel(const float* __restrict__ x,
                                                     const float* __restrict__ xs,
                                                     const float* __restrict__ feat,
                                                     const float* __restrict__ fs,
                                                     const int* __restrict__ knn,
                                                     double* __restrict__ acc_xk,
                                                     double* __restrict__ acc_fk, int S, int N) {
  int k = threadIdx.x & 31;
  int qs = threadIdx.x >> 5;  // 0..7
  int qbase = blockIdx.x * 32;
  double sx = 0, sxx = 0, sf = 0, sff = 0;
  for (int jj = 0; jj < 4; ++jj) {
    int q = qbase + qs * 4 + jj;
    int b = q / S;
    int nbr = knn[(size_t)q * 32 + k];
    const float* xr = x + ((size_t)b * N + nbr) * 3;
    const float* xq = xs + (size_t)q * 3;
#pragma unroll
    for (int c = 0; c < 3; ++c) {
      float d = xr[c] - xq[c];
      sx += (double)d;
      sxx += (double)d * (double)d;
    }
    const float4* fr = (const float4*)(feat + ((size_t)b * N + nbr) * C);
    const float4* fq = (const float4*)(fs + (size_t)q * C);
    for (int c = 0; c < C / 4; ++c) {
      float4 a = fr[c], bb = fq[c];
      float d0 = a.x - bb.x, d1 = a.y - bb.y, d2 = a.z - bb.z, d3 = a.w - bb.w;
      sf += (double)d0 + (double)d1 + (double)d2 + (double)d3;
      sff += (double)d0 * d0 + (double)d1 * d1 + (double)d2 * d2 + (double)d3 * d3;
    }
  }
  __shared__ double red[256];
  double vals[4] = {sx, sxx, sf, sff};
  double rr[4] = {0, 0, 0, 0};
#pragma unroll
  for (int p = 0; p < 4; ++p) {
    red[threadIdx.x] = vals[p];
    __syncthreads();
    if (threadIdx.x < 32) {
      double r = 0;
#pragma unroll
      for (int t = 0; t < 8; ++t) r += red[k + t * 32];
      rr[p] = r;
    }
    __syncthreads();
  }
  if (threadIdx.x < 32) {
    atomicAdd(&acc_xk[k * 2 + 0], rr[0]);
    atomicAdd(&acc_xk[k * 2 + 1], rr[1]);
    atomicAdd(&acc_fk[k * 2 + 0], rr[2]);
    atomicAdd(&acc_fk[k * 2 + 1], rr[3]);
  }
}

__global__ void finish_std(const double* __restrict__ acc_xk, const double* __restrict__ acc_fk,
                           float* __restrict__ pstd, int n1, int n2) {
  int k = threadIdx.x;
  if (k < 32) {
    double s = acc_xk[k * 2], ss = acc_xk[k * 2 + 1];
    double var = (ss - s * s / (double)n1) / (double)(n1 - 1);
    float st = (float)sqrt(var > 0.0 ? var : 0.0);
    st = fmaxf(st, 1e-5f);
    pstd[k] = 1.0f / st;
    s = acc_fk[k * 2];
    ss = acc_fk[k * 2 + 1];
    var = (ss - s * s / (double)n2) / (double)(n2 - 1);
    st = (float)sqrt(var > 0.0 ? var : 0.0);
    st = fmaxf(st, 1e-5f);
    pstd[32 + k] = 1.0f / st;
  }
}

// ================= gstd stats over normalized xk =================
__global__ __launch_bounds__(256) void stats2_kernel(const float* __restrict__ x,
                                                     const float* __restrict__ xs,
                                                     const int* __restrict__ knn,
                                                     const float* __restrict__ pstd,
                                                     double* __restrict__ acc_g, int S, int N) {
  int b = blockIdx.y;
  int total = S * 32;
  double a[3] = {0, 0, 0}, qq[3] = {0, 0, 0};
  for (int u = blockIdx.x * 256 + threadIdx.x; u < total; u += 32 * 256) {
    int s = u >> 5, k = u & 31;
    int nbr = knn[((size_t)b * S + s) * 32 + k];
    float is = pstd[k];
#pragma unroll
    for (int c = 0; c < 3; ++c) {
      float v = (x[((size_t)b * N + nbr) * 3 + c] - xs[((size_t)b * S + s) * 3 + c]) * is;
      a[c] += (double)v;
      qq[c] += (double)v * (double)v;
    }
  }
  __shared__ double red[256];
#pragma unroll
  for (int c = 0; c < 3; ++c) {
    red[threadIdx.x] = a[c];
    __syncthreads();
    for (int off = 128; off > 0; off >>= 1) {
      if (threadIdx.x < off) red[threadIdx.x] += red[threadIdx.x + off];
      __syncthreads();
    }
    if (threadIdx.x == 0) atomicAdd(&acc_g[(b * 3 + c) * 2], red[0]);
    __syncthreads();
    red[threadIdx.x] = qq[c];
    __syncthreads();
    for (int off = 128; off > 0; off >>= 1) {
      if (threadIdx.x < off) red[threadIdx.x] += red[threadIdx.x + off];
      __syncthreads();
    }
    if (threadIdx.x == 0) atomicAdd(&acc_g[(b * 3 + c) * 2 + 1], red[0]);
    __syncthreads();
  }
}

// gstd (24 slots of n samples each) -> params {inv(asig+eps), blend}
__global__ void finish_gstd(const double* __restrict__ acc, float* __restrict__ params, int n) {
  if (threadIdx.x == 0 && blockIdx.x == 0) {
    double g = 0;
    for (int i = 0; i < 24; ++i) {
      double s = acc[i * 2], ss = acc[i * 2 + 1];
      double var = (ss - s * s / (double)n) / (double)(n - 1);
      g += sqrt(var > 0.0 ? var : 0.0);
    }
    float gstd = (float)(g / 24.0);
    float asig = 0.26f * (1.0f + gstd);
    params[0] = 1.0f / (asig + 1e-6f);
    params[1] = 1.0f / (1.0f + expf(-(gstd - 0.1f) * 10.0f));
  }
}

// ================= init stats + init embed =================
__global__ __launch_bounds__(256) void init_stats(const float* __restrict__ xyz,
                                                  double* __restrict__ acc) {
  int bc = blockIdx.x;
  int b = bc / 3, c = bc - b * 3;
  double s = 0, ss = 0;
  for (int n = threadIdx.x; n < 4096; n += 256) {
    float v = xyz[((size_t)b * 4096 + n) * 3 + c];
    s += (double)v;
    ss += (double)v * (double)v;
  }
  __shared__ double r1[256], r2[256];
  r1[threadIdx.x] = s;
  r2[threadIdx.x] = ss;
  __syncthreads();
  for (int off = 128; off > 0; off >>= 1) {
    if (threadIdx.x < off) {
      r1[threadIdx.x] += r1[threadIdx.x + off];
      r2[threadIdx.x] += r2[threadIdx.x + off];
    }
    __syncthreads();
  }
  if (threadIdx.x == 0) {
    acc[bc * 2] = r1[0];
    acc[bc * 2 + 1] = r2[0];
  }
}

__global__ __launch_bounds__(256) void init_embed(const float* __restrict__ xyz,
                                                  const float* __restrict__ params,
                                                  float* __restrict__ feat) {
  int t = blockIdx.x * 256 + threadIdx.x;  // over 8*4096*64
  int j = t & 63;
  int n = (t >> 6) & 4095;
  int b = t >> 18;
  float inv_ae = params[0], blend = params[1];
  int idx = (int)((double)j * 65.0 / 63.0);
  int c = idx / 22, f = idx - c * 22;
  float fv = (float)(-1.0 + 2.0 * (double)(f + 1) / 23.0);
  float v = xyz[((size_t)b * 4096 + n) * 3 + c];
  float z = (v - fv) * inv_ae;
  float e = __expf(-0.5f * z * z);
  float co = __cosf(z);
  feat[t] = blend * e + (1.0f - blend) * co;
}

// ================= fused embed + gate + K-reduce + gelu =================
template <int C, int TWOC, int BLK, int FD>
__global__ __launch_bounds__(BLK) void fused_kernel(const float* __restrict__ x,
                                                    const float* __restrict__ xs,
                                                    const float* __restrict__ feat_in,
                                                    const float* __restrict__ fs,
                                                    const int* __restrict__ knn,
                                                    const float* __restrict__ pstd,
                                                    float* __restrict__ feat_out, int S, int N) {
  constexpr int JPT = TWOC / BLK;
  int q = blockIdx.x;
  int b = q / S;
  int tid = threadIdx.x;
  float inv_ae = pstd[64];
  float blend = pstd[65];
  float omb = 1.0f - blend;
  float c0 = xs[(size_t)q * 3 + 0];
  float c1 = xs[(size_t)q * 3 + 1];
  float c2 = xs[(size_t)q * 3 + 2];

  int cj[JPT];
  float fvj[JPT], fj[JPT], sum[JPT], mx[JPT];
#pragma unroll
  for (int i = 0; i < JPT; ++i) {
    int j = tid + i * BLK;
    int idx = (int)((double)j * (double)(3 * FD - 1) / (double)(TWOC - 1));
    int c = idx / FD, f = idx - c * FD;
    cj[i] = c;
    fvj[i] = (float)(-1.0 + 2.0 * (double)(f + 1) / (double)(FD + 1));
    fj[i] = fs[(size_t)q * C + (j < C ? j : j - C)];
    sum[i] = 0.0f;
    mx[i] = -3.4e38f;
  }

  const int* krow = knn + (size_t)q * 32;
#pragma unroll 1
  for (int k = 0; k < 32; ++k) {
    int nbr = krow[k];
    float isx = pstd[k], isf = pstd[32 + k];
    const float* xr = x + ((size_t)b * N + nbr) * 3;
    float xk0 = (xr[0] - c0) * isx;
    float xk1 = (xr[1] - c1) * isx;
    float xk2 = (xr[2] - c2) * isx;
    const float* fr = feat_in + ((size_t)b * N + nbr) * C;
#pragma unroll
    for (int i = 0; i < JPT; ++i) {
      int j = tid + i * BLK;
      float cat;
      if (j < C)
        cat = (fr[j] - fj[i]) * isf;
      else
        cat = fj[i];
      float xc = (cj[i] == 0) ? xk0 : ((cj[i] == 1) ? xk1 : xk2);
      float z = (xc - fvj[i]) * inv_ae;
      float comb = blend * __expf(-0.5f * z * z) + omb * __cosf(z);
      float fw = (cat + comb) * comb;
      sum[i] += fw;
      mx[i] = fmaxf(mx[i], fw);
    }
  }
#pragma unroll
  for (int i = 0; i < JPT; ++i) {
    float val = sum[i] * 0.03125f + mx[i];
    float g = 0.5f * val * (1.0f + erff(val * 0.7071067811865476f));
    feat_out[(size_t)q * TWOC + tid + i * BLK] = g;
  }
}

// ================= stage result reduce (max & mean over S) =================
template <int TWOC, int BLK>
__global__ __launch_bounds__(BLK) void result_partial(const float* __restrict__ feat,
                                                      float* __restrict__ pmax,
                                                      double* __restrict__ psum, int S) {
  int j = blockIdx.x * BLK + threadIdx.x;
  int ch = blockIdx.y, b = blockIdx.z;
  int rows = S >> 3;
  int s0 = ch * rows;
  float m = -3.4e38f;
  double sd = 0.0;
  for (int s = 0; s < rows; ++s) {
    float v = feat[((size_t)(b * S + s0 + s)) * TWOC + j];
    m = fmaxf(m, v);
    sd += (double)v;
  }
  pmax[((size_t)ch * 8 + b) * TWOC + j] = m;
  psum[((size_t)ch * 8 + b) * TWOC + j] = sd;
}

__global__ void result_final(const float* __restrict__ pmax, const double* __restrict__ psum,
                             float* __restrict__ out, int TWOC, int off, int S) {
  int t = blockIdx.x * 256 + threadIdx.x;
  if (t >= 8 * TWOC) return;
  int b = t / TWOC, j = t - b * TWOC;
  float m = -3.4e38f;
  double sd = 0.0;
  for (int ch = 0; ch < 8; ++ch) {
    m = fmaxf(m, pmax[((size_t)ch * 8 + b) * TWOC + j]);
    sd += psum[((size_t)ch * 8 + b) * TWOC + j];
  }
  out[(size_t)b * 3840 + off + j] = m;
  out[(size_t)b * 3840 + off + TWOC + j] = (float)(sd / (double)S);
}

// ================= stage driver =================
template <int N, int S, int C, int TWOC, int FD, int FBLK, int FP, int KP, int BLKF>
static void run_stage(const float* x, const float* feat_in, float* xs, float* fs, float* feat_out,
                      int* fps, int* knnb, double* accz, float* pstd, float* pmax, double* psum,
                      float* out, int outoff, hipStream_t stream) {
  static_assert(FBLK * FP == N, "fps size");
  static_assert(64 * KP == N, "knn size");
  double* acc_xk = accz;
  double* acc_fk = accz + 64;
  double* acc_g = accz + 128;

  fps_kernel<FBLK, FP><<<8, FBLK, 0, stream>>>(x, fps, S);
  gather_xs_kernel<<<(8 * S * 3 + 255) / 256, 256, 0, stream>>>(x, fps, xs, S, N);
  gather_fs_kernel<<<(8 * S * C) / 256, 256, 0, stream>>>(feat_in, fps, fs, S, N, C);
  knn_kernel<KP><<<(8 * S) / 4, 256, 0, stream>>>(x, xs, knnb, S);
  hipMemsetAsync(accz, 0, 1408, stream);
  stats1_kernel<C><<<(8 * S) / 32, 256, 0, stream>>>(x, xs, feat_in, fs, knnb, acc_xk, acc_fk, S, N);
  finish_std<<<1, 64, 0, stream>>>(acc_xk, acc_fk, pstd, 8 * S * 3, 8 * S * C);
  stats2_kernel<<<dim3(32, 8), 256, 0, stream>>>(x, xs, knnb, pstd, acc_g, S, N);
  finish_gstd<<<1, 64, 0, stream>>>(acc_g, pstd + 64, S * 32);
  fused_kernel<C, TWOC, BLKF, FD><<<8 * S, BLKF, 0, stream>>>(x, xs, feat_in, fs, knnb, pstd,
                                                              feat_out, S, N);
  constexpr int RBLK = (TWOC < 256) ? TWOC : 256;
  result_partial<TWOC, RBLK><<<dim3(TWOC / RBLK, 8, 8), RBLK, 0, stream>>>(feat_out, pmax, psum, S);
  result_final<<<(8 * TWOC + 255) / 256, 256, 0, stream>>>(pmax, psum, out, TWOC, outoff, S);
}

extern "C" void kernel_launch(void* const* d_in, const int* in_sizes, int n_in, void* d_out,
                              int out_size, void* d_ws, size_t ws_size, hipStream_t stream) {
  (void)in_sizes;
  (void)n_in;
  (void)out_size;
  (void)ws_size;
  const float* xyz = (const float*)d_in[0];
  float* out = (float*)d_out;
  char* w = (char*)d_ws;

  float* featA = (float*)(w + WS_FEAT_A);
  float* featB = (float*)(w + WS_FEAT_B);
  float* xs0 = (float*)(w + WS_XS0);
  float* xs1 = (float*)(w + WS_XS1);
  float* fs = (float*)(w + WS_FS);
  int* fps = (int*)(w + WS_FPS);
  int* knnb = (int*)(w + WS_KNN);
  float* pmax = (float*)(w + WS_PMAX);
  double* psum = (double*)(w + WS_PSUM);
  double* accz = (double*)(w + WS_ACC);
  double* acci = (double*)(w + WS_ACCI);
  float* pstd = (float*)(w + WS_PSTD);
  float* pinit = (float*)(w + WS_PINIT);

  // initial adaptive embed of xyz -> feat [8,4096,64]
  init_stats<<<24, 256, 0, stream>>>(xyz, acci);
  finish_gstd<<<1, 64, 0, stream>>>(acci, pinit, 4096);
  init_embed<<<(8 * 4096 * 64) / 256, 256, 0, stream>>>(xyz, pinit, featA);

  // 4 stages
  run_stage<4096, 2048, 64, 128, 43, 512, 8, 64, 128>(xyz, featA, xs0, fs, featB, fps, knnb,
                                                      accz, pstd, pmax, psum, out, 0, stream);
  run_stage<2048, 1024, 128, 256, 86, 256, 8, 32, 256>(xs0, featB, xs1, fs, featA, fps, knnb,
                                                       accz, pstd, pmax, psum, out, 256, stream);
  run_stage<1024, 512, 256, 512, 171, 256, 4, 16, 256>(xs1, featA, xs0, fs, featB, fps, knnb,
                                                       accz, pstd, pmax, psum, out, 768, stream);
  run_stage<512, 256, 512, 1024, 342, 256, 2, 8, 256>(xs0, featB, xs1, fs, featA, fps, knnb,
                                                      accz, pstd, pmax, psum, out, 1792, stream);
}

// Round 3
// 4499.132 us; speedup vs baseline: 1.2342x; 1.0686x over previous
//
#include <hip/hip_runtime.h>

typedef unsigned int u32;
typedef unsigned long long u64;

// ---------------- workspace layout (bytes) ----------------
#define WS_FEAT_A   0            // 2,097,152 f32 (8.39 MB)
#define WS_FEAT_B   8388608      // 2,097,152 f32
#define WS_XS0      16777216     // 49,152 f32
#define WS_XS1      16973824     // 49,152 f32
#define WS_FS       17170432     // 1,048,576 f32
#define WS_FPS      21364736     // 16,384 i32
#define WS_KNN      21430272     // 524,288 i32
#define WS_PMAX     23527424     // 8*8*1024 f32
#define WS_PSUM     23789568     // 8*8*1024 f64
#define WS_ACC      24313856     // zeroed per stage: acc_xk(64 dbl) acc_fk(64 dbl) acc_g(48 dbl)
#define WS_ACCI     24315392     // 48 dbl (init stats)
#define WS_PSTD     24315776     // 128 f32: [0..31] inv_std_xk, [32..63] inv_std_fk, [64] inv_ae, [65] blend
#define WS_PINIT    24316288     // 2 f32

// ---- DPP wave64 reductions (VALU, ~70cy total vs ~720cy for LDS butterflies) ----
// canonical GCN sequence: row_shr 1/2/4/8 then row_bcast 15/31; result in lane 63.
__device__ __forceinline__ u32 dpp_umax_l63(u32 v) {
  u32 t;
  t = (u32)__builtin_amdgcn_update_dpp(0, (int)v, 0x111, 0xf, 0xf, true); v = v > t ? v : t;
  t = (u32)__builtin_amdgcn_update_dpp(0, (int)v, 0x112, 0xf, 0xf, true); v = v > t ? v : t;
  t = (u32)__builtin_amdgcn_update_dpp(0, (int)v, 0x114, 0xf, 0xf, true); v = v > t ? v : t;
  t = (u32)__builtin_amdgcn_update_dpp(0, (int)v, 0x118, 0xf, 0xf, true); v = v > t ? v : t;
  t = (u32)__builtin_amdgcn_update_dpp(0, (int)v, 0x142, 0xf, 0xf, true); v = v > t ? v : t;
  t = (u32)__builtin_amdgcn_update_dpp(0, (int)v, 0x143, 0xf, 0xf, true); v = v > t ? v : t;
  return (u32)__builtin_amdgcn_readlane((int)v, 63);
}

__device__ __forceinline__ u32 dpp_umin_l63(u32 v) {
  u32 t;
  t = (u32)__builtin_amdgcn_update_dpp(-1, (int)v, 0x111, 0xf, 0xf, false); v = v < t ? v : t;
  t = (u32)__builtin_amdgcn_update_dpp(-1, (int)v, 0x112, 0xf, 0xf, false); v = v < t ? v : t;
  t = (u32)__builtin_amdgcn_update_dpp(-1, (int)v, 0x114, 0xf, 0xf, false); v = v < t ? v : t;
  t = (u32)__builtin_amdgcn_update_dpp(-1, (int)v, 0x118, 0xf, 0xf, false); v = v < t ? v : t;
  t = (u32)__builtin_amdgcn_update_dpp(-1, (int)v, 0x142, 0xf, 0xf, false); v = v < t ? v : t;
  t = (u32)__builtin_amdgcn_update_dpp(-1, (int)v, 0x143, 0xf, 0xf, false); v = v < t ? v : t;
  return (u32)__builtin_amdgcn_readlane((int)v, 63);
}

// ---- strict (non-contracted) float math matching numpy op order ----
__device__ __forceinline__ float dist2_nc(float ax, float ay, float az,
                                          float bx, float by, float bz) {
#pragma clang fp contract(off)
  float dx = ax - bx, dy = ay - by, dz = az - bz;
  float d = dx * dx;
  d = d + dy * dy;
  d = d + dz * dz;
  return d;
}

__device__ __forceinline__ float sumsq3_nc(float x, float y, float z) {
#pragma clang fp contract(off)
  float d = x * x;
  d = d + y * y;
  d = d + z * z;
  return d;
}

__device__ __forceinline__ float knn_dist_nc(float qx, float qy, float qz, float qsq,
                                             float nx, float ny, float nz) {
#pragma clang fp contract(off)
  float dot = qx * nx;
  dot = dot + qy * ny;
  dot = dot + qz * nz;
  float nsq = nx * nx;
  nsq = nsq + ny * ny;
  nsq = nsq + nz * nz;
  float d = -2.0f * dot;
  d = d + qsq;
  d = d + nsq;
  return d;
}

// ================= FPS =================
// one block per batch; exact pointnet2 semantics (start at index 0).
// Round: dist update + local argmax (coords tracked in regs) -> DPP u32-max of
// dist bits (valid: dists >= 0) -> readlane -> ballot tie-break (exact argmax
// first-occurrence) -> [NW>1: owner writes {dbits,inv,coords} to parity LDS
// slot, ONE barrier, b128 read + select]  [NW==1: coords via same-address L1
// load, no LDS, no barrier].
template <int BLK, int P>
__global__ __launch_bounds__(BLK) void fps_kernel(const float* __restrict__ x,
                                                  int* __restrict__ out_idx, int S) {
  constexpr int NW = BLK / 64;
  const int N = BLK * P;
  const int b = blockIdx.x;
  const float* xb = x + (size_t)b * N * 3;
  const int tid = threadIdx.x;
  const int lane = tid & 63;
  const int wid = tid >> 6;

  float px[P], py[P], pz[P], dist[P];
#pragma unroll
  for (int i = 0; i < P; ++i) {
    int idx = i * BLK + tid;
    px[i] = xb[idx * 3 + 0];
    py[i] = xb[idx * 3 + 1];
    pz[i] = xb[idx * 3 + 2];
    dist[i] = 1e10f;
  }

  __shared__ u32 sred[2][NW][8];  // {dbits, inv, cx, cy, cz, pad...} per wave, parity dbuf

  if (tid == 0) out_idx[b * S + 0] = 0;
  float lx = xb[0], ly = xb[1], lz = xb[2];

#pragma unroll 1
  for (int it = 1; it < S; ++it) {
    const int p = it & 1;
    // --- dist update + thread-local argmax (strict > keeps smallest idx) ---
    float d0 = dist2_nc(px[0], py[0], pz[0], lx, ly, lz);
    float dm0 = fminf(dist[0], d0);
    dist[0] = dm0;
    u32 bd = __float_as_uint(dm0);
    u32 binv = 0xFFFFFFFFu - (u32)tid;
    float bx = px[0], by = py[0], bz = pz[0];
#pragma unroll
    for (int i = 1; i < P; ++i) {
      float d = dist2_nc(px[i], py[i], pz[i], lx, ly, lz);
      float dm = fminf(dist[i], d);
      dist[i] = dm;
      u32 db = __float_as_uint(dm);
      if (db > bd) {
        bd = db;
        binv = 0xFFFFFFFFu - (u32)(i * BLK + tid);
        bx = px[i]; by = py[i]; bz = pz[i];
      }
    }
    // --- wave argmax: DPP max of dist bits + exact tie-break ---
    u32 maxb = dpp_umax_l63(bd);
    u64 cm = __ballot(bd == maxb);
    u32 winv;
    if (__popcll(cm) == 1) {
      winv = (u32)__builtin_amdgcn_readlane((int)binv, (int)__ffsll((long long)cm) - 1);
    } else {
      winv = dpp_umax_l63(bd == maxb ? binv : 0u);  // max inv == min idx among ties
    }

    if constexpr (NW > 1) {
      // owner lane (unique: inv unique per lane) stashes key + coords
      if (bd == maxb && binv == winv) {
        uint4 pk;
        pk.x = maxb; pk.y = winv;
        pk.z = __float_as_uint(bx); pk.w = __float_as_uint(by);
        *(uint4*)&sred[p][wid][0] = pk;
        sred[p][wid][4] = __float_as_uint(bz);
      }
      __syncthreads();
      uint4 A = *(const uint4*)&sred[p][0][0];
      u32 a4 = sred[p][0][4];
#pragma unroll
      for (int w = 1; w < NW; ++w) {
        uint4 B = *(const uint4*)&sred[p][w][0];
        u32 b4 = sred[p][w][4];
        bool gt = (B.x > A.x) || (B.x == A.x && B.y > A.y);
        if (gt) { A = B; a4 = b4; }
      }
      lx = __uint_as_float(A.z);
      ly = __uint_as_float(A.w);
      lz = __uint_as_float(a4);
      if (tid == 0) out_idx[b * S + it] = (int)(0xFFFFFFFFu - A.y);
    } else {
      u32 widx = 0xFFFFFFFFu - winv;
      if (lane == 0) out_idx[b * S + it] = (int)widx;
      // same-address broadcast load, L1-resident
      lx = xb[widx * 3 + 0];
      ly = xb[widx * 3 + 1];
      lz = xb[widx * 3 + 2];
    }
  }
}

// ================= gathers =================
__global__ __launch_bounds__(256) void gather_xs_kernel(const float* __restrict__ x,
                                                        const int* __restrict__ fidx,
                                                        float* __restrict__ xs, int S, int N) {
  int t = blockIdx.x * 256 + threadIdx.x;
  if (t >= 8 * S * 3) return;
  int c = t % 3;
  int q = t / 3;
  int b = q / S;
  xs[t] = x[((size_t)b * N + fidx[q]) * 3 + c];
}

__global__ __launch_bounds__(256) void gather_fs_kernel(const float* __restrict__ feat,
                                                        const int* __restrict__ fidx,
                                                        float* __restrict__ fs, int S, int N, int C) {
  int t = blockIdx.x * 256 + threadIdx.x;
  if (t >= 8 * S * C) return;
  int c = t & (C - 1);
  int q = t / C;
  int b = q / S;
  fs[t] = feat[((size_t)b * N + fidx[q]) * C + c];
}

// ================= kNN (wave per query; DPP-min round reduce, exact order) ==
template <int P>  // N = 64*P candidates
__global__ __launch_bounds__(256) void knn_kernel(const float* __restrict__ x,
                                                  const float* __restrict__ xs,
                                                  int* __restrict__ knn, int S) {
  int wave = threadIdx.x >> 6, lane = threadIdx.x & 63;
  int q = blockIdx.x * 4 + wave;
  int b = q / S;
  const int N = 64 * P;
  const float* xb = x + (size_t)b * N * 3;
  float qx = xs[(size_t)q * 3 + 0];
  float qy = xs[(size_t)q * 3 + 1];
  float qz = xs[(size_t)q * 3 + 2];
  float qsq = sumsq3_nc(qx, qy, qz);

  u64 key[P];
#pragma unroll
  for (int i = 0; i < P; ++i) {
    int idx = i * 64 + lane;
    float nx = xb[idx * 3 + 0], ny = xb[idx * 3 + 1], nz = xb[idx * 3 + 2];
    float d = knn_dist_nc(qx, qy, qz, qsq, nx, ny, nz);
    u32 u = __float_as_uint(d);
    u32 msk = ((u32)(((int)u) >> 31)) | 0x80000000u;  // sortable float mapping (handles tiny negatives)
    u ^= msk;
    key[i] = ((u64)u << 32) | (u64)(u32)idx;
  }

  u64 prev = 0;
  u32 myv = 0;
#pragma unroll 1
  for (int r = 0; r < 32; ++r) {
    u64 best = ~0ull;
#pragma unroll
    for (int i = 0; i < P; ++i) {
      u64 k = key[i];
      u64 cand = (k > prev) ? k : ~0ull;
      best = (cand < best) ? cand : best;
    }
    // cand >= K (true next key) for all lanes => hi(cand) >= hi(K); exact.
    u32 hi = (u32)(best >> 32);
    u32 minb = dpp_umin_l63(hi);
    u64 cm = __ballot(hi == minb);
    u32 lo;
    if (__popcll(cm) == 1) {
      lo = (u32)__builtin_amdgcn_readlane((int)(u32)best, (int)__ffsll((long long)cm) - 1);
    } else {
      lo = dpp_umin_l63(hi == minb ? (u32)best : 0xFFFFFFFFu);
    }
    prev = ((u64)minb << 32) | lo;
    if (lane == r) myv = lo;
  }
  if (lane < 32) knn[(size_t)q * 32 + lane] = (int)myv;
}

// ================= per-k std stats (xk and fk) =================
template <int C>
__global__ __launch_bounds__(256) void stats1_kernel(const float* __restrict__ x,
                                                     const float* __restrict__ xs,
                                                     const float* __restrict__ feat,
                                                     const float* __restrict__ fs,
                                                     const int* __restrict__ knn,
                                                     double* __restrict__ acc_xk,
                                                     double* __restrict__ acc_fk, int S, int N) {
  int k = threadIdx.x & 31;
  int qs = threadIdx.x >> 5;  // 0..7
  int qbase = blockIdx.x * 32;
  double sx = 0, sxx = 0, sf = 0, sff = 0;
  for (int jj = 0; jj < 4; ++jj) {
    int q = qbase + qs * 4 + jj;
    int b = q / S;
    int nbr = knn[(size_t)q * 32 + k];
    const float* xr = x + ((size_t)b * N + nbr) * 3;
    const float* xq = xs + (size_t)q * 3;
#pragma unroll
    for (int c = 0; c < 3; ++c) {
      float d = xr[c] - xq[c];
      sx += (double)d;
      sxx += (double)d * (double)d;
    }
    const float4* fr = (const float4*)(feat + ((size_t)b * N + nbr) * C);
    const float4* fq = (const float4*)(fs + (size_t)q * C);
    for (int c = 0; c < C / 4; ++c) {
      float4 a = fr[c], bb = fq[c];
      float d0 = a.x - bb.x, d1 = a.y - bb.y, d2 = a.z - bb.z, d3 = a.w - bb.w;
      sf += (double)d0 + (double)d1 + (double)d2 + (double)d3;
      sff += (double)d0 * d0 + (double)d1 * d1 + (double)d2 * d2 + (double)d3 * d3;
    }
  }
  __shared__ double red[256];
  double vals[4] = {sx, sxx, sf, sff};
  double rr[4] = {0, 0, 0, 0};
#pragma unroll
  for (int p = 0; p < 4; ++p) {
    red[threadIdx.x] = vals[p];
    __syncthreads();
    if (threadIdx.x < 32) {
      double r = 0;
#pragma unroll
      for (int t = 0; t < 8; ++t) r += red[k + t * 32];
      rr[p] = r;
    }
    __syncthreads();
  }
  if (threadIdx.x < 32) {
    atomicAdd(&acc_xk[k * 2 + 0], rr[0]);
    atomicAdd(&acc_xk[k * 2 + 1], rr[1]);
    atomicAdd(&acc_fk[k * 2 + 0], rr[2]);
    atomicAdd(&acc_fk[k * 2 + 1], rr[3]);
  }
}

__global__ void finish_std(const double* __restrict__ acc_xk, const double* __restrict__ acc_fk,
                           float* __restrict__ pstd, int n1, int n2) {
  int k = threadIdx.x;
  if (k < 32) {
    double s = acc_xk[k * 2], ss = acc_xk[k * 2 + 1];
    double var = (ss - s * s / (double)n1) / (double)(n1 - 1);
    float st = (float)sqrt(var > 0.0 ? var : 0.0);
    st = fmaxf(st, 1e-5f);
    pstd[k] = 1.0f / st;
    s = acc_fk[k * 2];
    ss = acc_fk[k * 2 + 1];
    var = (ss - s * s / (double)n2) / (double)(n2 - 1);
    st = (float)sqrt(var > 0.0 ? var : 0.0);
    st = fmaxf(st, 1e-5f);
    pstd[32 + k] = 1.0f / st;
  }
}

// ================= gstd stats over normalized xk =================
__global__ __launch_bounds__(256) void stats2_kernel(const float* __restrict__ x,
                                                     const float* __restrict__ xs,
                                                     const int* __restrict__ knn,
                                                     const float* __restrict__ pstd,
                                                     double* __restrict__ acc_g, int S, int N) {
  int b = blockIdx.y;
  int total = S * 32;
  double a[3] = {0, 0, 0}, qq[3] = {0, 0, 0};
  for (int u = blockIdx.x * 256 + threadIdx.x; u < total; u += 32 * 256) {
    int s = u >> 5, k = u & 31;
    int nbr = knn[((size_t)b * S + s) * 32 + k];
    float is = pstd[k];
#pragma unroll
    for (int c = 0; c < 3; ++c) {
      float v = (x[((size_t)b * N + nbr) * 3 + c] - xs[((size_t)b * S + s) * 3 + c]) * is;
      a[c] += (double)v;
      qq[c] += (double)v * (double)v;
    }
  }
  __shared__ double red[256];
#pragma unroll
  for (int c = 0; c < 3; ++c) {
    red[threadIdx.x] = a[c];
    __syncthreads();
    for (int off = 128; off > 0; off >>= 1) {
      if (threadIdx.x < off) red[threadIdx.x] += red[threadIdx.x + off];
      __syncthreads();
    }
    if (threadIdx.x == 0) atomicAdd(&acc_g[(b * 3 + c) * 2], red[0]);
    __syncthreads();
    red[threadIdx.x] = qq[c];
    __syncthreads();
    for (int off = 128; off > 0; off >>= 1) {
      if (threadIdx.x < off) red[threadIdx.x] += red[threadIdx.x + off];
      __syncthreads();
    }
    if (threadIdx.x == 0) atomicAdd(&acc_g[(b * 3 + c) * 2 + 1], red[0]);
    __syncthreads();
  }
}

// gstd (24 slots of n samples each) -> params {inv(asig+eps), blend}
__global__ void finish_gstd(const double* __restrict__ acc, float* __restrict__ params, int n) {
  if (threadIdx.x == 0 && blockIdx.x == 0) {
    double g = 0;
    for (int i = 0; i < 24; ++i) {
      double s = acc[i * 2], ss = acc[i * 2 + 1];
      double var = (ss - s * s / (double)n) / (double)(n - 1);
      g += sqrt(var > 0.0 ? var : 0.0);
    }
    float gstd = (float)(g / 24.0);
    float asig = 0.26f * (1.0f + gstd);
    params[0] = 1.0f / (asig + 1e-6f);
    params[1] = 1.0f / (1.0f + expf(-(gstd - 0.1f) * 10.0f));
  }
}

// ================= init stats + init embed =================
__global__ __launch_bounds__(256) void init_stats(const float* __restrict__ xyz,
                                                  double* __restrict__ acc) {
  int bc = blockIdx.x;
  int b = bc / 3, c = bc - b * 3;
  double s = 0, ss = 0;
  for (int n = threadIdx.x; n < 4096; n += 256) {
    float v = xyz[((size_t)b * 4096 + n) * 3 + c];
    s += (double)v;
    ss += (double)v * (double)v;
  }
  __shared__ double r1[256], r2[256];
  r1[threadIdx.x] = s;
  r2[threadIdx.x] = ss;
  __syncthreads();
  for (int off = 128; off > 0; off >>= 1) {
    if (threadIdx.x < off) {
      r1[threadIdx.x] += r1[threadIdx.x + off];
      r2[threadIdx.x] += r2[threadIdx.x + off];
    }
    __syncthreads();
  }
  if (threadIdx.x == 0) {
    acc[bc * 2] = r1[0];
    acc[bc * 2 + 1] = r2[0];
  }
}

__global__ __launch_bounds__(256) void init_embed(const float* __restrict__ xyz,
                                                  const float* __restrict__ params,
                                                  float* __restrict__ feat) {
  int t = blockIdx.x * 256 + threadIdx.x;  // over 8*4096*64
  int j = t & 63;
  int n = (t >> 6) & 4095;
  int b = t >> 18;
  float inv_ae = params[0], blend = params[1];
  int idx = (int)((double)j * 65.0 / 63.0);
  int c = idx / 22, f = idx - c * 22;
  float fv = (float)(-1.0 + 2.0 * (double)(f + 1) / 23.0);
  float v = xyz[((size_t)b * 4096 + n) * 3 + c];
  float z = (v - fv) * inv_ae;
  float e = __expf(-0.5f * z * z);
  float co = __cosf(z);
  feat[t] = blend * e + (1.0f - blend) * co;
}

// ================= fused embed + gate + K-reduce + gelu =================
template <int C, int TWOC, int BLK, int FD>
__global__ __launch_bounds__(BLK) void fused_kernel(const float* __restrict__ x,
                                                    const float* __restrict__ xs,
                                                    const float* __restrict__ feat_in,
                                                    const float* __restrict__ fs,
                                                    const int* __restrict__ knn,
                                                    const float* __restrict__ pstd,
                                                    float* __restrict__ feat_out, int S, int N) {
  constexpr int JPT = TWOC / BLK;
  int q = blockIdx.x;
  int b = q / S;
  int tid = threadIdx.x;
  float inv_ae = pstd[64];
  float blend = pstd[65];
  float omb = 1.0f - blend;
  float c0 = xs[(size_t)q * 3 + 0];
  float c1 = xs[(size_t)q * 3 + 1];
  float c2 = xs[(size_t)q * 3 + 2];

  int cj[JPT];
  float fvj[JPT], fj[JPT], sum[JPT], mx[JPT];
#pragma unroll
  for (int i = 0; i < JPT; ++i) {
    int j = tid + i * BLK;
    int idx = (int)((double)j * (double)(3 * FD - 1) / (double)(TWOC - 1));
    int c = idx / FD, f = idx - c * FD;
    cj[i] = c;
    fvj[i] = (float)(-1.0 + 2.0 * (double)(f + 1) / (double)(FD + 1));
    fj[i] = fs[(size_t)q * C + (j < C ? j : j - C)];
    sum[i] = 0.0f;
    mx[i] = -3.4e38f;
  }

  const int* krow = knn + (size_t)q * 32;
#pragma unroll 1
  for (int k = 0; k < 32; ++k) {
    int nbr = krow[k];
    float isx = pstd[k], isf = pstd[32 + k];
    const float* xr = x + ((size_t)b * N + nbr) * 3;
    float xk0 = (xr[0] - c0) * isx;
    float xk1 = (xr[1] - c1) * isx;
    float xk2 = (xr[2] - c2) * isx;
    const float* fr = feat_in + ((size_t)b * N + nbr) * C;
#pragma unroll
    for (int i = 0; i < JPT; ++i) {
      int j = tid + i * BLK;
      float cat;
      if (j < C)
        cat = (fr[j] - fj[i]) * isf;
      else
        cat = fj[i];
      float xc = (cj[i] == 0) ? xk0 : ((cj[i] == 1) ? xk1 : xk2);
      float z = (xc - fvj[i]) * inv_ae;
      float comb = blend * __expf(-0.5f * z * z) + omb * __cosf(z);
      float fw = (cat + comb) * comb;
      sum[i] += fw;
      mx[i] = fmaxf(mx[i], fw);
    }
  }
#pragma unroll
  for (int i = 0; i < JPT; ++i) {
    float val = sum[i] * 0.03125f + mx[i];
    float g = 0.5f * val * (1.0f + erff(val * 0.7071067811865476f));
    feat_out[(size_t)q * TWOC + tid + i * BLK] = g;
  }
}

// ================= stage result reduce (max & mean over S) =================
template <int TWOC, int BLK>
__global__ __launch_bounds__(BLK) void result_partial(const float* __restrict__ feat,
                                                      float* __restrict__ pmax,
                                                      double* __restrict__ psum, int S) {
  int j = blockIdx.x * BLK + threadIdx.x;
  int ch = blockIdx.y, b = blockIdx.z;
  int rows = S >> 3;
  int s0 = ch * rows;
  float m = -3.4e38f;
  double sd = 0.0;
  for (int s = 0; s < rows; ++s) {
    float v = feat[((size_t)(b * S + s0 + s)) * TWOC + j];
    m = fmaxf(m, v);
    sd += (double)v;
  }
  pmax[((size_t)ch * 8 + b) * TWOC + j] = m;
  psum[((size_t)ch * 8 + b) * TWOC + j] = sd;
}

__global__ void result_final(const float* __restrict__ pmax, const double* __restrict__ psum,
                             float* __restrict__ out, int TWOC, int off, int S) {
  int t = blockIdx.x * 256 + threadIdx.x;
  if (t >= 8 * TWOC) return;
  int b = t / TWOC, j = t - b * TWOC;
  float m = -3.4e38f;
  double sd = 0.0;
  for (int ch = 0; ch < 8; ++ch) {
    m = fmaxf(m, pmax[((size_t)ch * 8 + b) * TWOC + j]);
    sd += psum[((size_t)ch * 8 + b) * TWOC + j];
  }
  out[(size_t)b * 3840 + off + j] = m;
  out[(size_t)b * 3840 + off + TWOC + j] = (float)(sd / (double)S);
}

// ================= stage driver =================
template <int N, int S, int C, int TWOC, int FD, int FBLK, int FP, int KP, int BLKF>
static void run_stage(const float* x, const float* feat_in, float* xs, float* fs, float* feat_out,
                      int* fps, int* knnb, double* accz, float* pstd, float* pmax, double* psum,
                      float* out, int outoff, hipStream_t stream) {
  static_assert(FBLK * FP == N, "fps size");
  static_assert(64 * KP == N, "knn size");
  double* acc_xk = accz;
  double* acc_fk = accz + 64;
  double* acc_g = accz + 128;

  fps_kernel<FBLK, FP><<<8, FBLK, 0, stream>>>(x, fps, S);
  gather_xs_kernel<<<(8 * S * 3 + 255) / 256, 256, 0, stream>>>(x, fps, xs, S, N);
  gather_fs_kernel<<<(8 * S * C) / 256, 256, 0, stream>>>(feat_in, fps, fs, S, N, C);
  knn_kernel<KP><<<(8 * S) / 4, 256, 0, stream>>>(x, xs, knnb, S);
  hipMemsetAsync(accz, 0, 1408, stream);
  stats1_kernel<C><<<(8 * S) / 32, 256, 0, stream>>>(x, xs, feat_in, fs, knnb, acc_xk, acc_fk, S, N);
  finish_std<<<1, 64, 0, stream>>>(acc_xk, acc_fk, pstd, 8 * S * 3, 8 * S * C);
  stats2_kernel<<<dim3(32, 8), 256, 0, stream>>>(x, xs, knnb, pstd, acc_g, S, N);
  finish_gstd<<<1, 64, 0, stream>>>(acc_g, pstd + 64, S * 32);
  fused_kernel<C, TWOC, BLKF, FD><<<8 * S, BLKF, 0, stream>>>(x, xs, feat_in, fs, knnb, pstd,
                                                              feat_out, S, N);
  constexpr int RBLK = (TWOC < 256) ? TWOC : 256;
  result_partial<TWOC, RBLK><<<dim3(TWOC / RBLK, 8, 8), RBLK, 0, stream>>>(feat_out, pmax, psum, S);
  result_final<<<(8 * TWOC + 255) / 256, 256, 0, stream>>>(pmax, psum, out, TWOC, outoff, S);
}

extern "C" void kernel_launch(void* const* d_in, const int* in_sizes, int n_in, void* d_out,
                              int out_size, void* d_ws, size_t ws_size, hipStream_t stream) {
  (void)in_sizes;
  (void)n_in;
  (void)out_size;
  (void)ws_size;
  const float* xyz = (const float*)d_in[0];
  float* out = (float*)d_out;
  char* w = (char*)d_ws;

  float* featA = (float*)(w + WS_FEAT_A);
  float* featB = (float*)(w + WS_FEAT_B);
  float* xs0 = (float*)(w + WS_XS0);
  float* xs1 = (float*)(w + WS_XS1);
  float* fs = (float*)(w + WS_FS);
  int* fps = (int*)(w + WS_FPS);
  int* knnb = (int*)(w + WS_KNN);
  float* pmax = (float*)(w + WS_PMAX);
  double* psum = (double*)(w + WS_PSUM);
  double* accz = (double*)(w + WS_ACC);
  double* acci = (double*)(w + WS_ACCI);
  float* pstd = (float*)(w + WS_PSTD);
  float* pinit = (float*)(w + WS_PINIT);

  // initial adaptive embed of xyz -> feat [8,4096,64]
  init_stats<<<24, 256, 0, stream>>>(xyz, acci);
  finish_gstd<<<1, 64, 0, stream>>>(acci, pinit, 4096);
  init_embed<<<(8 * 4096 * 64) / 256, 256, 0, stream>>>(xyz, pinit, featA);

  // 4 stages
  run_stage<4096, 2048, 64, 128, 43, 512, 8, 64, 128>(xyz, featA, xs0, fs, featB, fps, knnb,
                                                      accz, pstd, pmax, psum, out, 0, stream);
  run_stage<2048, 1024, 128, 256, 86, 256, 8, 32, 256>(xs0, featB, xs1, fs, featA, fps, knnb,
                                                       accz, pstd, pmax, psum, out, 256, stream);
  run_stage<1024, 512, 256, 512, 171, 64, 16, 16, 256>(xs1, featA, xs0, fs, featB, fps, knnb,
                                                       accz, pstd, pmax, psum, out, 768, stream);
  run_stage<512, 256, 512, 1024, 342, 64, 8, 8, 256>(xs0, featB, xs1, fs, featA, fps, knnb,
                                                     accz, pstd, pmax, psum, out, 1792, stream);
}

// Round 5
// 3206.948 us; speedup vs baseline: 1.7314x; 1.4029x over previous
//
#include <hip/hip_runtime.h>

typedef unsigned int u32;
typedef unsigned long long u64;

// ---------------- workspace layout (bytes) ----------------
#define WS_FEAT_A   0            // 2,097,152 f32 (8.39 MB)
#define WS_FEAT_B   8388608      // 2,097,152 f32
#define WS_XS0      16777216     // 49,152 f32
#define WS_XS1      16973824     // 49,152 f32
#define WS_FS       17170432     // 1,048,576 f32
#define WS_FPS      21364736     // 16,384 i32
#define WS_KNN      21430272     // 524,288 i32
#define WS_PMAX     23527424     // 8*8*1024 f32
#define WS_PSUM     23789568     // 8*8*1024 f64
#define WS_ACC      24313856     // zeroed per stage: acc_xk(64 dbl) acc_fk(64 dbl) acc_g(48 dbl)
#define WS_ACCI     24315392     // 48 dbl (init stats)
#define WS_PSTD     24315776     // 128 f32: [0..31] inv_std_xk, [32..63] inv_std_fk, [64] inv_ae, [65] blend
#define WS_PINIT    24316288     // 2 f32

// ---- DPP wave64 reductions (VALU) ----
// canonical GCN sequence: row_shr 1/2/4/8 then row_bcast 15/31; result in lane 63.
__device__ __forceinline__ u32 dpp_umax_l63(u32 v) {
  u32 t;
  t = (u32)__builtin_amdgcn_update_dpp(0, (int)v, 0x111, 0xf, 0xf, true); v = v > t ? v : t;
  t = (u32)__builtin_amdgcn_update_dpp(0, (int)v, 0x112, 0xf, 0xf, true); v = v > t ? v : t;
  t = (u32)__builtin_amdgcn_update_dpp(0, (int)v, 0x114, 0xf, 0xf, true); v = v > t ? v : t;
  t = (u32)__builtin_amdgcn_update_dpp(0, (int)v, 0x118, 0xf, 0xf, true); v = v > t ? v : t;
  t = (u32)__builtin_amdgcn_update_dpp(0, (int)v, 0x142, 0xf, 0xf, true); v = v > t ? v : t;
  t = (u32)__builtin_amdgcn_update_dpp(0, (int)v, 0x143, 0xf, 0xf, true); v = v > t ? v : t;
  return (u32)__builtin_amdgcn_readlane((int)v, 63);
}

__device__ __forceinline__ u32 dpp_umin_l63(u32 v) {
  u32 t;
  t = (u32)__builtin_amdgcn_update_dpp(-1, (int)v, 0x111, 0xf, 0xf, false); v = v < t ? v : t;
  t = (u32)__builtin_amdgcn_update_dpp(-1, (int)v, 0x112, 0xf, 0xf, false); v = v < t ? v : t;
  t = (u32)__builtin_amdgcn_update_dpp(-1, (int)v, 0x114, 0xf, 0xf, false); v = v < t ? v : t;
  t = (u32)__builtin_amdgcn_update_dpp(-1, (int)v, 0x118, 0xf, 0xf, false); v = v < t ? v : t;
  t = (u32)__builtin_amdgcn_update_dpp(-1, (int)v, 0x142, 0xf, 0xf, false); v = v < t ? v : t;
  t = (u32)__builtin_amdgcn_update_dpp(-1, (int)v, 0x143, 0xf, 0xf, false); v = v < t ? v : t;
  return (u32)__builtin_amdgcn_readlane((int)v, 63);
}

// ---- strict (non-contracted) float math matching numpy op order ----
__device__ __forceinline__ float dist2_nc(float ax, float ay, float az,
                                          float bx, float by, float bz) {
#pragma clang fp contract(off)
  float dx = ax - bx, dy = ay - by, dz = az - bz;
  float d = dx * dx;
  d = d + dy * dy;
  d = d + dz * dz;
  return d;
}

__device__ __forceinline__ float sumsq3_nc(float x, float y, float z) {
#pragma clang fp contract(off)
  float d = x * x;
  d = d + y * y;
  d = d + z * z;
  return d;
}

__device__ __forceinline__ float knn_dist_nc(float qx, float qy, float qz, float qsq,
                                             float nx, float ny, float nz) {
#pragma clang fp contract(off)
  float dot = qx * nx;
  dot = dot + qy * ny;
  dot = dot + qz * nz;
  float nsq = nx * nx;
  nsq = nsq + ny * ny;
  nsq = nsq + nz * nz;
  float d = -2.0f * dot;
  d = d + qsq;
  d = d + nsq;
  return d;
}

// ================= FPS =================
// one block per batch; exact pointnet2 semantics (start at index 0).
// Per-round critical path (minimized LDS + VALU):
//   dist update + local argmax over (dist_bits, small_i)  [~12 VALU/point]
//   -> DPP u32-max of dist bits (valid: dists >= 0)
//   -> unique-max fast path: readlane(global idx, ffs(ballot))  [tie path rare,
//      wave-uniform branch, exact argmax-first-occurrence semantics]
//   -> NW>1: lane0 ds_write_b64 {maxbits, inv_idx}; ONE barrier; every thread
//      reads NW contiguous u64 keys (2x ds_read_b128) + u64-max merge.
//   -> winner coords: ONE broadcast ds_read_b128 from float4 point cache in LDS.
// Parity double-buffered key slots make the single barrier sufficient (a
// writer of slot[p] at round it+2 has passed barrier(it+1), which round-it
// readers of slot[p] contributed to only after finishing their reads).
template <int BLK, int P>
__global__ __launch_bounds__(BLK) void fps_kernel(const float* __restrict__ x,
                                                  int* __restrict__ out_idx, int S) {
  constexpr int NW = BLK / 64;
  const int N = BLK * P;
  const int b = blockIdx.x;
  const float* xb = x + (size_t)b * N * 3;
  const int tid = threadIdx.x;
  const int lane = tid & 63;
  const int wid = tid >> 6;

  __shared__ float4 spts[BLK * P];
  __shared__ alignas(16) u64 skey[2][NW < 2 ? 2 : NW];

  float px[P], py[P], pz[P], dist[P];
#pragma unroll
  for (int i = 0; i < P; ++i) {
    int idx = i * BLK + tid;
    px[i] = xb[idx * 3 + 0];
    py[i] = xb[idx * 3 + 1];
    pz[i] = xb[idx * 3 + 2];
    dist[i] = 1e10f;
    spts[idx] = make_float4(px[i], py[i], pz[i], 0.0f);
  }
  __syncthreads();

  if (tid == 0) out_idx[b * S + 0] = 0;
  float4 l4 = spts[0];
  float lx = l4.x, ly = l4.y, lz = l4.z;

#pragma unroll 1
  for (int it = 1; it < S; ++it) {
    const int p = it & 1;
    // --- dist update + thread-local argmax (strict > keeps smallest idx) ---
    float d0 = dist2_nc(px[0], py[0], pz[0], lx, ly, lz);
    float dm0 = fminf(dist[0], d0);
    dist[0] = dm0;
    u32 bd = __float_as_uint(dm0);
    int bi = 0;
#pragma unroll
    for (int i = 1; i < P; ++i) {
      float d = dist2_nc(px[i], py[i], pz[i], lx, ly, lz);
      float dm = fminf(dist[i], d);
      dist[i] = dm;
      u32 db = __float_as_uint(dm);
      bool g = db > bd;
      bd = g ? db : bd;
      bi = g ? i : bi;
    }
    u32 bidx = (u32)(bi * BLK + tid);

    // --- wave argmax: DPP max of dist bits + exact tie handling ---
    u32 maxb = dpp_umax_l63(bd);
    u64 cm = __ballot(bd == maxb);
    u32 widx;
    if (__popcll(cm) == 1) {
      widx = (u32)__builtin_amdgcn_readlane((int)bidx, (int)__ffsll((long long)cm) - 1);
    } else {
      widx = 0xFFFFFFFFu - dpp_umax_l63((bd == maxb) ? (0xFFFFFFFFu - bidx) : 0u);
    }

    if constexpr (NW > 1) {
      if (lane == 0) skey[p][wid] = ((u64)maxb << 32) | (u64)(0xFFFFFFFFu - widx);
      __syncthreads();
      u64 best = skey[p][0];
#pragma unroll
      for (int w = 1; w < NW; ++w) {
        u64 kk = skey[p][w];
        best = (kk > best) ? kk : best;
      }
      widx = 0xFFFFFFFFu - (u32)best;
      if (tid == 0) out_idx[b * S + it] = (int)widx;
    } else {
      if (lane == 0) out_idx[b * S + it] = (int)widx;
    }

    // --- winner coords: single broadcast LDS read ---
    float4 c4 = spts[widx];
    lx = c4.x;
    ly = c4.y;
    lz = c4.z;
  }
}

// ================= gathers =================
__global__ __launch_bounds__(256) void gather_xs_kernel(const float* __restrict__ x,
                                                        const int* __restrict__ fidx,
                                                        float* __restrict__ xs, int S, int N) {
  int t = blockIdx.x * 256 + threadIdx.x;
  if (t >= 8 * S * 3) return;
  int c = t % 3;
  int q = t / 3;
  int b = q / S;
  xs[t] = x[((size_t)b * N + fidx[q]) * 3 + c];
}

__global__ __launch_bounds__(256) void gather_fs_kernel(const float* __restrict__ feat,
                                                        const int* __restrict__ fidx,
                                                        float* __restrict__ fs, int S, int N, int C) {
  int t = blockIdx.x * 256 + threadIdx.x;
  if (t >= 8 * S * C) return;
  int c = t & (C - 1);
  int q = t / C;
  int b = q / S;
  fs[t] = feat[((size_t)b * N + fidx[q]) * C + c];
}

// ================= kNN (wave per query; DPP-min round reduce, exact order) ==
template <int P>  // N = 64*P candidates
__global__ __launch_bounds__(256) void knn_kernel(const float* __restrict__ x,
                                                  const float* __restrict__ xs,
                                                  int* __restrict__ knn, int S) {
  int wave = threadIdx.x >> 6, lane = threadIdx.x & 63;
  int q = blockIdx.x * 4 + wave;
  int b = q / S;
  const int N = 64 * P;
  const float* xb = x + (size_t)b * N * 3;
  float qx = xs[(size_t)q * 3 + 0];
  float qy = xs[(size_t)q * 3 + 1];
  float qz = xs[(size_t)q * 3 + 2];
  float qsq = sumsq3_nc(qx, qy, qz);

  u64 key[P];
#pragma unroll
  for (int i = 0; i < P; ++i) {
    int idx = i * 64 + lane;
    float nx = xb[idx * 3 + 0], ny = xb[idx * 3 + 1], nz = xb[idx * 3 + 2];
    float d = knn_dist_nc(qx, qy, qz, qsq, nx, ny, nz);
    u32 u = __float_as_uint(d);
    u32 msk = ((u32)(((int)u) >> 31)) | 0x80000000u;  // sortable float mapping (handles tiny negatives)
    u ^= msk;
    key[i] = ((u64)u << 32) | (u64)(u32)idx;
  }

  u64 prev = 0;
  u32 myv = 0;
#pragma unroll 1
  for (int r = 0; r < 32; ++r) {
    u64 best = ~0ull;
#pragma unroll
    for (int i = 0; i < P; ++i) {
      u64 k = key[i];
      u64 cand = (k > prev) ? k : ~0ull;
      best = (cand < best) ? cand : best;
    }
    // cand >= K (true next key) for all lanes => hi(cand) >= hi(K); exact.
    u32 hi = (u32)(best >> 32);
    u32 minb = dpp_umin_l63(hi);
    u64 cm = __ballot(hi == minb);
    u32 lo;
    if (__popcll(cm) == 1) {
      lo = (u32)__builtin_amdgcn_readlane((int)(u32)best, (int)__ffsll((long long)cm) - 1);
    } else {
      lo = dpp_umin_l63(hi == minb ? (u32)best : 0xFFFFFFFFu);
    }
    prev = ((u64)minb << 32) | lo;
    if (lane == r) myv = lo;
  }
  if (lane < 32) knn[(size_t)q * 32 + lane] = (int)myv;
}

// ================= per-k std stats (xk and fk) =================
template <int C>
__global__ __launch_bounds__(256) void stats1_kernel(const float* __restrict__ x,
                                                     const float* __restrict__ xs,
                                                     const float* __restrict__ feat,
                                                     const float* __restrict__ fs,
                                                     const int* __restrict__ knn,
                                                     double* __restrict__ acc_xk,
                                                     double* __restrict__ acc_fk, int S, int N) {
  int k = threadIdx.x & 31;
  int qs = threadIdx.x >> 5;  // 0..7
  int qbase = blockIdx.x * 32;
  double sx = 0, sxx = 0, sf = 0, sff = 0;
  for (int jj = 0; jj < 4; ++jj) {
    int q = qbase + qs * 4 + jj;
    int b = q / S;
    int nbr = knn[(size_t)q * 32 + k];
    const float* xr = x + ((size_t)b * N + nbr) * 3;
    const float* xq = xs + (size_t)q * 3;
#pragma unroll
    for (int c = 0; c < 3; ++c) {
      float d = xr[c] - xq[c];
      sx += (double)d;
      sxx += (double)d * (double)d;
    }
    const float4* fr = (const float4*)(feat + ((size_t)b * N + nbr) * C);
    const float4* fq = (const float4*)(fs + (size_t)q * C);
    for (int c = 0; c < C / 4; ++c) {
      float4 a = fr[c], bb = fq[c];
      float d0 = a.x - bb.x, d1 = a.y - bb.y, d2 = a.z - bb.z, d3 = a.w - bb.w;
      sf += (double)d0 + (double)d1 + (double)d2 + (double)d3;
      sff += (double)d0 * d0 + (double)d1 * d1 + (double)d2 * d2 + (double)d3 * d3;
    }
  }
  __shared__ double red[256];
  double vals[4] = {sx, sxx, sf, sff};
  double rr[4] = {0, 0, 0, 0};
#pragma unroll
  for (int p = 0; p < 4; ++p) {
    red[threadIdx.x] = vals[p];
    __syncthreads();
    if (threadIdx.x < 32) {
      double r = 0;
#pragma unroll
      for (int t = 0; t < 8; ++t) r += red[k + t * 32];
      rr[p] = r;
    }
    __syncthreads();
  }
  if (threadIdx.x < 32) {
    atomicAdd(&acc_xk[k * 2 + 0], rr[0]);
    atomicAdd(&acc_xk[k * 2 + 1], rr[1]);
    atomicAdd(&acc_fk[k * 2 + 0], rr[2]);
    atomicAdd(&acc_fk[k * 2 + 1], rr[3]);
  }
}

__global__ void finish_std(const double* __restrict__ acc_xk, const double* __restrict__ acc_fk,
                           float* __restrict__ pstd, int n1, int n2) {
  int k = threadIdx.x;
  if (k < 32) {
    double s = acc_xk[k * 2], ss = acc_xk[k * 2 + 1];
    double var = (ss - s * s / (double)n1) / (double)(n1 - 1);
    float st = (float)sqrt(var > 0.0 ? var : 0.0);
    st = fmaxf(st, 1e-5f);
    pstd[k] = 1.0f / st;
    s = acc_fk[k * 2];
    ss = acc_fk[k * 2 + 1];
    var = (ss - s * s / (double)n2) / (double)(n2 - 1);
    st = (float)sqrt(var > 0.0 ? var : 0.0);
    st = fmaxf(st, 1e-5f);
    pstd[32 + k] = 1.0f / st;
  }
}

// ================= gstd stats over normalized xk =================
__global__ __launch_bounds__(256) void stats2_kernel(const float* __restrict__ x,
                                                     const float* __restrict__ xs,
                                                     const int* __restrict__ knn,
                                                     const float* __restrict__ pstd,
                                                     double* __restrict__ acc_g, int S, int N) {
  int b = blockIdx.y;
  int total = S * 32;
  double a[3] = {0, 0, 0}, qq[3] = {0, 0, 0};
  for (int u = blockIdx.x * 256 + threadIdx.x; u < total; u += 32 * 256) {
    int s = u >> 5, k = u & 31;
    int nbr = knn[((size_t)b * S + s) * 32 + k];
    float is = pstd[k];
#pragma unroll
    for (int c = 0; c < 3; ++c) {
      float v = (x[((size_t)b * N + nbr) * 3 + c] - xs[((size_t)b * S + s) * 3 + c]) * is;
      a[c] += (double)v;
      qq[c] += (double)v * (double)v;
    }
  }
  __shared__ double red[256];
#pragma unroll
  for (int c = 0; c < 3; ++c) {
    red[threadIdx.x] = a[c];
    __syncthreads();
    for (int off = 128; off > 0; off >>= 1) {
      if (threadIdx.x < off) red[threadIdx.x] += red[threadIdx.x + off];
      __syncthreads();
    }
    if (threadIdx.x == 0) atomicAdd(&acc_g[(b * 3 + c) * 2], red[0]);
    __syncthreads();
    red[threadIdx.x] = qq[c];
    __syncthreads();
    for (int off = 128; off > 0; off >>= 1) {
      if (threadIdx.x < off) red[threadIdx.x] += red[threadIdx.x + off];
      __syncthreads();
    }
    if (threadIdx.x == 0) atomicAdd(&acc_g[(b * 3 + c) * 2 + 1], red[0]);
    __syncthreads();
  }
}

// gstd (24 slots of n samples each) -> params {inv(asig+eps), blend}
__global__ void finish_gstd(const double* __restrict__ acc, float* __restrict__ params, int n) {
  if (threadIdx.x == 0 && blockIdx.x == 0) {
    double g = 0;
    for (int i = 0; i < 24; ++i) {
      double s = acc[i * 2], ss = acc[i * 2 + 1];
      double var = (ss - s * s / (double)n) / (double)(n - 1);
      g += sqrt(var > 0.0 ? var : 0.0);
    }
    float gstd = (float)(g / 24.0);
    float asig = 0.26f * (1.0f + gstd);
    params[0] = 1.0f / (asig + 1e-6f);
    params[1] = 1.0f / (1.0f + expf(-(gstd - 0.1f) * 10.0f));
  }
}

// ================= init stats + init embed =================
__global__ __launch_bounds__(256) void init_stats(const float* __restrict__ xyz,
                                                  double* __restrict__ acc) {
  int bc = blockIdx.x;
  int b = bc / 3, c = bc - b * 3;
  double s = 0, ss = 0;
  for (int n = threadIdx.x; n < 4096; n += 256) {
    float v = xyz[((size_t)b * 4096 + n) * 3 + c];
    s += (double)v;
    ss += (double)v * (double)v;
  }
  __shared__ double r1[256], r2[256];
  r1[threadIdx.x] = s;
  r2[threadIdx.x] = ss;
  __syncthreads();
  for (int off = 128; off > 0; off >>= 1) {
    if (threadIdx.x < off) {
      r1[threadIdx.x] += r1[threadIdx.x + off];
      r2[threadIdx.x] += r2[threadIdx.x + off];
    }
    __syncthreads();
  }
  if (threadIdx.x == 0) {
    acc[bc * 2] = r1[0];
    acc[bc * 2 + 1] = r2[0];
  }
}

__global__ __launch_bounds__(256) void init_embed(const float* __restrict__ xyz,
                                                  const float* __restrict__ params,
                                                  float* __restrict__ feat) {
  int t = blockIdx.x * 256 + threadIdx.x;  // over 8*4096*64
  int j = t & 63;
  int n = (t >> 6) & 4095;
  int b = t >> 18;
  float inv_ae = params[0], blend = params[1];
  int idx = (int)((double)j * 65.0 / 63.0);
  int c = idx / 22, f = idx - c * 22;
  float fv = (float)(-1.0 + 2.0 * (double)(f + 1) / 23.0);
  float v = xyz[((size_t)b * 4096 + n) * 3 + c];
  float z = (v - fv) * inv_ae;
  float e = __expf(-0.5f * z * z);
  float co = __cosf(z);
  feat[t] = blend * e + (1.0f - blend) * co;
}

// ================= fused embed + gate + K-reduce + gelu =================
template <int C, int TWOC, int BLK, int FD>
__global__ __launch_bounds__(BLK) void fused_kernel(const float* __restrict__ x,
                                                    const float* __restrict__ xs,
                                                    const float* __restrict__ feat_in,
                                                    const float* __restrict__ fs,
                                                    const int* __restrict__ knn,
                                                    const float* __restrict__ pstd,
                                                    float* __restrict__ feat_out, int S, int N) {
  constexpr int JPT = TWOC / BLK;
  int q = blockIdx.x;
  int b = q / S;
  int tid = threadIdx.x;
  float inv_ae = pstd[64];
  float blend = pstd[65];
  float omb = 1.0f - blend;
  float c0 = xs[(size_t)q * 3 + 0];
  float c1 = xs[(size_t)q * 3 + 1];
  float c2 = xs[(size_t)q * 3 + 2];

  int cj[JPT];
  float fvj[JPT], fj[JPT], sum[JPT], mx[JPT];
#pragma unroll
  for (int i = 0; i < JPT; ++i) {
    int j = tid + i * BLK;
    int idx = (int)((double)j * (double)(3 * FD - 1) / (double)(TWOC - 1));
    int c = idx / FD, f = idx - c * FD;
    cj[i] = c;
    fvj[i] = (float)(-1.0 + 2.0 * (double)(f + 1) / (double)(FD + 1));
    fj[i] = fs[(size_t)q * C + (j < C ? j : j - C)];
    sum[i] = 0.0f;
    mx[i] = -3.4e38f;
  }

  const int* krow = knn + (size_t)q * 32;
#pragma unroll 1
  for (int k = 0; k < 32; ++k) {
    int nbr = krow[k];
    float isx = pstd[k], isf = pstd[32 + k];
    const float* xr = x + ((size_t)b * N + nbr) * 3;
    float xk0 = (xr[0] - c0) * isx;
    float xk1 = (xr[1] - c1) * isx;
    float xk2 = (xr[2] - c2) * isx;
    const float* fr = feat_in + ((size_t)b * N + nbr) * C;
#pragma unroll
    for (int i = 0; i < JPT; ++i) {
      int j = tid + i * BLK;
      float cat;
      if (j < C)
        cat = (fr[j] - fj[i]) * isf;
      else
        cat = fj[i];
      float xc = (cj[i] == 0) ? xk0 : ((cj[i] == 1) ? xk1 : xk2);
      float z = (xc - fvj[i]) * inv_ae;
      float comb = blend * __expf(-0.5f * z * z) + omb * __cosf(z);
      float fw = (cat + comb) * comb;
      sum[i] += fw;
      mx[i] = fmaxf(mx[i], fw);
    }
  }
#pragma unroll
  for (int i = 0; i < JPT; ++i) {
    float val = sum[i] * 0.03125f + mx[i];
    float g = 0.5f * val * (1.0f + erff(val * 0.7071067811865476f));
    feat_out[(size_t)q * TWOC + tid + i * BLK] = g;
  }
}

// ================= stage result reduce (max & mean over S) =================
template <int TWOC, int BLK>
__global__ __launch_bounds__(BLK) void result_partial(const float* __restrict__ feat,
                                                      float* __restrict__ pmax,
                                                      double* __restrict__ psum, int S) {
  int j = blockIdx.x * BLK + threadIdx.x;
  int ch = blockIdx.y, b = blockIdx.z;
  int rows = S >> 3;
  int s0 = ch * rows;
  float m = -3.4e38f;
  double sd = 0.0;
  for (int s = 0; s < rows; ++s) {
    float v = feat[((size_t)(b * S + s0 + s)) * TWOC + j];
    m = fmaxf(m, v);
    sd += (double)v;
  }
  pmax[((size_t)ch * 8 + b) * TWOC + j] = m;
  psum[((size_t)ch * 8 + b) * TWOC + j] = sd;
}

__global__ void result_final(const float* __restrict__ pmax, const double* __restrict__ psum,
                             float* __restrict__ out, int TWOC, int off, int S) {
  int t = blockIdx.x * 256 + threadIdx.x;
  if (t >= 8 * TWOC) return;
  int b = t / TWOC, j = t - b * TWOC;
  float m = -3.4e38f;
  double sd = 0.0;
  for (int ch = 0; ch < 8; ++ch) {
    m = fmaxf(m, pmax[((size_t)ch * 8 + b) * TWOC + j]);
    sd += psum[((size_t)ch * 8 + b) * TWOC + j];
  }
  out[(size_t)b * 3840 + off + j] = m;
  out[(size_t)b * 3840 + off + TWOC + j] = (float)(sd / (double)S);
}

// ================= stage driver =================
template <int N, int S, int C, int TWOC, int FD, int FBLK, int FP, int KP, int BLKF>
static void run_stage(const float* x, const float* feat_in, float* xs, float* fs, float* feat_out,
                      int* fps, int* knnb, double* accz, float* pstd, float* pmax, double* psum,
                      float* out, int outoff, hipStream_t stream) {
  static_assert(FBLK * FP == N, "fps size");
  static_assert(64 * KP == N, "knn size");
  double* acc_xk = accz;
  double* acc_fk = accz + 64;
  double* acc_g = accz + 128;

  fps_kernel<FBLK, FP><<<8, FBLK, 0, stream>>>(x, fps, S);
  gather_xs_kernel<<<(8 * S * 3 + 255) / 256, 256, 0, stream>>>(x, fps, xs, S, N);
  gather_fs_kernel<<<(8 * S * C) / 256, 256, 0, stream>>>(feat_in, fps, fs, S, N, C);
  knn_kernel<KP><<<(8 * S) / 4, 256, 0, stream>>>(x, xs, knnb, S);
  hipMemsetAsync(accz, 0, 1408, stream);
  stats1_kernel<C><<<(8 * S) / 32, 256, 0, stream>>>(x, xs, feat_in, fs, knnb, acc_xk, acc_fk, S, N);
  finish_std<<<1, 64, 0, stream>>>(acc_xk, acc_fk, pstd, 8 * S * 3, 8 * S * C);
  stats2_kernel<<<dim3(32, 8), 256, 0, stream>>>(x, xs, knnb, pstd, acc_g, S, N);
  finish_gstd<<<1, 64, 0, stream>>>(acc_g, pstd + 64, S * 32);
  fused_kernel<C, TWOC, BLKF, FD><<<8 * S, BLKF, 0, stream>>>(x, xs, feat_in, fs, knnb, pstd,
                                                              feat_out, S, N);
  constexpr int RBLK = (TWOC < 256) ? TWOC : 256;
  result_partial<TWOC, RBLK><<<dim3(TWOC / RBLK, 8, 8), RBLK, 0, stream>>>(feat_out, pmax, psum, S);
  result_final<<<(8 * TWOC + 255) / 256, 256, 0, stream>>>(pmax, psum, out, TWOC, outoff, S);
}

extern "C" void kernel_launch(void* const* d_in, const int* in_sizes, int n_in, void* d_out,
                              int out_size, void* d_ws, size_t ws_size, hipStream_t stream) {
  (void)in_sizes;
  (void)n_in;
  (void)out_size;
  (void)ws_size;
  const float* xyz = (const float*)d_in[0];
  float* out = (float*)d_out;
  char* w = (char*)d_ws;

  float* featA = (float*)(w + WS_FEAT_A);
  float* featB = (float*)(w + WS_FEAT_B);
  float* xs0 = (float*)(w + WS_XS0);
  float* xs1 = (float*)(w + WS_XS1);
  float* fs = (float*)(w + WS_FS);
  int* fps = (int*)(w + WS_FPS);
  int* knnb = (int*)(w + WS_KNN);
  float* pmax = (float*)(w + WS_PMAX);
  double* psum = (double*)(w + WS_PSUM);
  double* accz = (double*)(w + WS_ACC);
  double* acci = (double*)(w + WS_ACCI);
  float* pstd = (float*)(w + WS_PSTD);
  float* pinit = (float*)(w + WS_PINIT);

  // initial adaptive embed of xyz -> feat [8,4096,64]
  init_stats<<<24, 256, 0, stream>>>(xyz, acci);
  finish_gstd<<<1, 64, 0, stream>>>(acci, pinit, 4096);
  init_embed<<<(8 * 4096 * 64) / 256, 256, 0, stream>>>(xyz, pinit, featA);

  // 4 stages
  run_stage<4096, 2048, 64, 128, 43, 256, 16, 64, 128>(xyz, featA, xs0, fs, featB, fps, knnb,
                                                       accz, pstd, pmax, psum, out, 0, stream);
  run_stage<2048, 1024, 128, 256, 86, 256, 8, 32, 256>(xs0, featB, xs1, fs, featA, fps, knnb,
                                                       accz, pstd, pmax, psum, out, 256, stream);
  run_stage<1024, 512, 256, 512, 171, 64, 16, 16, 256>(xs1, featA, xs0, fs, featB, fps, knnb,
                                                       accz, pstd, pmax, psum, out, 768, stream);
  run_stage<512, 256, 512, 1024, 342, 64, 8, 8, 256>(xs0, featB, xs1, fs, featA, fps, knnb,
                                                     accz, pstd, pmax, psum, out, 1792, stream);
}

// Round 6
// 3156.424 us; speedup vs baseline: 1.7591x; 1.0160x over previous
//
#include <hip/hip_runtime.h>

typedef unsigned int u32;
typedef unsigned long long u64;
typedef float f32x2 __attribute__((ext_vector_type(2)));

// ---------------- workspace layout (bytes) ----------------
#define WS_FEAT_A   0            // 2,097,152 f32 (8.39 MB)
#define WS_FEAT_B   8388608      // 2,097,152 f32
#define WS_XS0      16777216     // 49,152 f32
#define WS_XS1      16973824     // 49,152 f32
#define WS_FS       17170432     // (unused now)
#define WS_FPS      21364736     // 16,384 i32
#define WS_KNN      21430272     // 524,288 i32
#define WS_PMAX     23527424     // 8*8*1024 f32
#define WS_PSUM     23789568     // 8*8*1024 f64
#define WS_ACC      24313856     // acc_xk(64 dbl) acc_fk(64 dbl) acc_g(48 dbl) = 176 dbl
#define WS_ACCI     24315392     // 48 dbl (init stats)
#define WS_PSTD     24315776     // 128 f32
#define WS_PINIT    24316288     // 2 f32

// ---- packed f32 (VOP3P) — exact IEEE mul/add on each half ----
__device__ __forceinline__ f32x2 pk_add(f32x2 a, f32x2 b) {
  f32x2 d;
  asm("v_pk_add_f32 %0, %1, %2" : "=v"(d) : "v"(a), "v"(b));
  return d;
}
__device__ __forceinline__ f32x2 pk_mul(f32x2 a, f32x2 b) {
  f32x2 d;
  asm("v_pk_mul_f32 %0, %1, %2" : "=v"(d) : "v"(a), "v"(b));
  return d;
}

// ---- DPP wave64 reductions (VALU) ----
__device__ __forceinline__ u32 dpp_umax_l63(u32 v) {
  u32 t;
  t = (u32)__builtin_amdgcn_update_dpp(0, (int)v, 0x111, 0xf, 0xf, true); v = t > v ? t : v;
  t = (u32)__builtin_amdgcn_update_dpp(0, (int)v, 0x112, 0xf, 0xf, true); v = t > v ? t : v;
  t = (u32)__builtin_amdgcn_update_dpp(0, (int)v, 0x114, 0xf, 0xf, true); v = t > v ? t : v;
  t = (u32)__builtin_amdgcn_update_dpp(0, (int)v, 0x118, 0xf, 0xf, true); v = t > v ? t : v;
  t = (u32)__builtin_amdgcn_update_dpp(0, (int)v, 0x142, 0xf, 0xf, true); v = t > v ? t : v;
  t = (u32)__builtin_amdgcn_update_dpp(0, (int)v, 0x143, 0xf, 0xf, true); v = t > v ? t : v;
  return (u32)__builtin_amdgcn_readlane((int)v, 63);
}

__device__ __forceinline__ u32 dpp_umin_l63(u32 v) {
  u32 t;
  t = (u32)__builtin_amdgcn_update_dpp(-1, (int)v, 0x111, 0xf, 0xf, false); v = t < v ? t : v;
  t = (u32)__builtin_amdgcn_update_dpp(-1, (int)v, 0x112, 0xf, 0xf, false); v = t < v ? t : v;
  t = (u32)__builtin_amdgcn_update_dpp(-1, (int)v, 0x114, 0xf, 0xf, false); v = t < v ? t : v;
  t = (u32)__builtin_amdgcn_update_dpp(-1, (int)v, 0x118, 0xf, 0xf, false); v = t < v ? t : v;
  t = (u32)__builtin_amdgcn_update_dpp(-1, (int)v, 0x142, 0xf, 0xf, false); v = t < v ? t : v;
  t = (u32)__builtin_amdgcn_update_dpp(-1, (int)v, 0x143, 0xf, 0xf, false); v = t < v ? t : v;
  return (u32)__builtin_amdgcn_readlane((int)v, 63);
}

// ---- strict (non-contracted) float math matching numpy op order ----
__device__ __forceinline__ float sumsq3_nc(float x, float y, float z) {
#pragma clang fp contract(off)
  float d = x * x;
  d = d + y * y;
  d = d + z * z;
  return d;
}

__device__ __forceinline__ float knn_dist_nc(float qx, float qy, float qz, float qsq,
                                             float nx, float ny, float nz) {
#pragma clang fp contract(off)
  float dot = qx * nx;
  dot = dot + qy * ny;
  dot = dot + qz * nz;
  float nsq = nx * nx;
  nsq = nsq + ny * ny;
  nsq = nsq + nz * nz;
  float d = -2.0f * dot;
  d = d + qsq;
  d = d + nsq;
  return d;
}

// ================= FPS =================
// one block per batch; exact pointnet2 semantics (start at index 0).
// Per-round: packed-f32 dist update (v_pk_*, bit-exact: a-b == a+(-b),
// (dx*dx+dy*dy)+dz*dz order preserved per half) + local argmax on u32 dist
// bits (valid: dists >= 0; strict > keeps smallest local idx) -> DPP u32-max
// -> ballot tie-break (exact argmax-first-occurrence) -> [NW>1: lane0
// ds_write_b64 wave key; ONE barrier; all threads read NW keys + u64-max
// merge] -> winner coords via ONE broadcast ds_read_b128 from LDS point
// cache. NO VMEM in the loop: selected indices buffered in LDS (sidx) and
// flushed at the end, so the barrier's implicit s_waitcnt vmcnt(0) never
// waits (global-store drain was ~200-400 cy/round in the previous version).
template <int BLK, int P>
__global__ __launch_bounds__(BLK) void fps_kernel(const float* __restrict__ x,
                                                  int* __restrict__ out_idx, int S) {
  constexpr int NW = BLK / 64;
  constexpr int PH = P / 2;
  const int N = BLK * P;
  const int b = blockIdx.x;
  const float* xb = x + (size_t)b * N * 3;
  const int tid = threadIdx.x;
  const int lane = tid & 63;
  const int wid = tid >> 6;

  __shared__ float4 spts[BLK * P];
  __shared__ alignas(16) u64 skey[2][NW < 2 ? 2 : NW];
  __shared__ int sidx[(NW > 1) ? (BLK * P / 2) : 1];

  f32x2 px2[PH], py2[PH], pz2[PH];
  float dist[P];
#pragma unroll
  for (int i = 0; i < P; ++i) {
    int idx = i * BLK + tid;
    float a = xb[idx * 3 + 0];
    float c = xb[idx * 3 + 1];
    float d = xb[idx * 3 + 2];
    px2[i >> 1][i & 1] = a;
    py2[i >> 1][i & 1] = c;
    pz2[i >> 1][i & 1] = d;
    dist[i] = 1e10f;
    spts[idx] = make_float4(a, c, d, 0.0f);
  }
  __syncthreads();

  if constexpr (NW == 1) {
    if (tid == 0) out_idx[b * S + 0] = 0;
  }
  float4 l4 = spts[0];
  float lx = l4.x, ly = l4.y, lz = l4.z;

#pragma unroll 1
  for (int it = 1; it < S; ++it) {
    const int p = it & 1;
    // --- packed dist update + thread-local argmax ---
    f32x2 vnx, vny, vnz;
    vnx[0] = vnx[1] = __uint_as_float(__float_as_uint(lx) ^ 0x80000000u);
    vny[0] = vny[1] = __uint_as_float(__float_as_uint(ly) ^ 0x80000000u);
    vnz[0] = vnz[1] = __uint_as_float(__float_as_uint(lz) ^ 0x80000000u);
    u32 bd = 0;
    int bi = 0;
#pragma unroll
    for (int j = 0; j < PH; ++j) {
      f32x2 dx = pk_add(px2[j], vnx);
      f32x2 dy = pk_add(py2[j], vny);
      f32x2 dz = pk_add(pz2[j], vnz);
      f32x2 m0 = pk_mul(dx, dx);
      f32x2 m1 = pk_mul(dy, dy);
      f32x2 m2 = pk_mul(dz, dz);
      f32x2 s = pk_add(pk_add(m0, m1), m2);
#pragma unroll
      for (int h = 0; h < 2; ++h) {
        int i = 2 * j + h;
        float dm = fminf(dist[i], s[h]);
        dist[i] = dm;
        u32 db = __float_as_uint(dm);
        bool g = db > bd;  // strict > keeps smallest local idx (argmax first-occurrence)
        bd = g ? db : bd;
        bi = g ? i : bi;
      }
    }
    u32 bidx = (u32)(bi * BLK + tid);

    // --- wave argmax: DPP max of dist bits + exact tie handling ---
    u32 maxb = dpp_umax_l63(bd);
    u64 cm = __ballot(bd == maxb);
    u32 widx;
    if (__popcll(cm) == 1) {
      widx = (u32)__builtin_amdgcn_readlane((int)bidx, (int)__ffsll((long long)cm) - 1);
    } else {
      widx = 0xFFFFFFFFu - dpp_umax_l63((bd == maxb) ? (0xFFFFFFFFu - bidx) : 0u);
    }

    if constexpr (NW > 1) {
      if (lane == 0) skey[p][wid] = ((u64)maxb << 32) | (u64)(0xFFFFFFFFu - widx);
      __syncthreads();
      u64 best = skey[p][0];
#pragma unroll
      for (int w = 1; w < NW; ++w) {
        u64 kk = skey[p][w];
        best = (kk > best) ? kk : best;
      }
      widx = 0xFFFFFFFFu - (u32)best;
      if (tid == 0) sidx[it] = (int)widx;  // LDS buffer, flushed at end
    } else {
      if (lane == 0) out_idx[b * S + it] = (int)widx;  // no barrier -> latency hidden
    }

    // --- winner coords: single broadcast LDS read ---
    float4 c4 = spts[widx];
    lx = c4.x;
    ly = c4.y;
    lz = c4.z;
  }

  if constexpr (NW > 1) {
    __syncthreads();
    for (int i = tid; i < S; i += BLK) out_idx[b * S + i] = (i == 0) ? 0 : sidx[i];
  }
}

// ================= gather (xs only; fs is read through fidx downstream) =====
__global__ __launch_bounds__(256) void gather_xs_kernel(const float* __restrict__ x,
                                                        const int* __restrict__ fidx,
                                                        float* __restrict__ xs, int S, int N) {
  int t = blockIdx.x * 256 + threadIdx.x;
  if (t >= 8 * S * 3) return;
  int c = t % 3;
  int q = t / 3;
  int b = q / S;
  xs[t] = x[((size_t)b * N + fidx[q]) * 3 + c];
}

// ================= kNN (wave per query; DPP-min round reduce, exact order) ==
template <int P>  // N = 64*P candidates
__global__ __launch_bounds__(256) void knn_kernel(const float* __restrict__ x,
                                                  const float* __restrict__ xs,
                                                  int* __restrict__ knn, int S) {
  int wave = threadIdx.x >> 6, lane = threadIdx.x & 63;
  int q = blockIdx.x * 4 + wave;
  int b = q / S;
  const int N = 64 * P;
  const float* xb = x + (size_t)b * N * 3;
  float qx = xs[(size_t)q * 3 + 0];
  float qy = xs[(size_t)q * 3 + 1];
  float qz = xs[(size_t)q * 3 + 2];
  float qsq = sumsq3_nc(qx, qy, qz);

  u64 key[P];
#pragma unroll
  for (int i = 0; i < P; ++i) {
    int idx = i * 64 + lane;
    float nx = xb[idx * 3 + 0], ny = xb[idx * 3 + 1], nz = xb[idx * 3 + 2];
    float d = knn_dist_nc(qx, qy, qz, qsq, nx, ny, nz);
    u32 u = __float_as_uint(d);
    u32 msk = ((u32)(((int)u) >> 31)) | 0x80000000u;  // sortable float mapping
    u ^= msk;
    key[i] = ((u64)u << 32) | (u64)(u32)idx;
  }

  u64 prev = 0;
  u32 myv = 0;
#pragma unroll 1
  for (int r = 0; r < 32; ++r) {
    u64 best = ~0ull;
#pragma unroll
    for (int i = 0; i < P; ++i) {
      u64 k = key[i];
      u64 cand = (k > prev) ? k : ~0ull;
      best = (cand < best) ? cand : best;
    }
    // cand >= K (true next key) for all lanes => hi(cand) >= hi(K); exact.
    u32 hi = (u32)(best >> 32);
    u32 minb = dpp_umin_l63(hi);
    u64 cm = __ballot(hi == minb);
    u32 lo;
    if (__popcll(cm) == 1) {
      lo = (u32)__builtin_amdgcn_readlane((int)(u32)best, (int)__ffsll((long long)cm) - 1);
    } else {
      lo = dpp_umin_l63(hi == minb ? (u32)best : 0xFFFFFFFFu);
    }
    prev = ((u64)minb << 32) | lo;
    if (lane == r) myv = lo;
  }
  if (lane < 32) knn[(size_t)q * 32 + lane] = (int)myv;
}

// ================= per-k std stats (xk and fk) =================
template <int C>
__global__ __launch_bounds__(256) void stats1_kernel(const float* __restrict__ x,
                                                     const float* __restrict__ xs,
                                                     const float* __restrict__ feat,
                                                     const int* __restrict__ fidx,
                                                     const int* __restrict__ knn,
                                                     double* __restrict__ acc_xk,
                                                     double* __restrict__ acc_fk, int S, int N) {
  int k = threadIdx.x & 31;
  int qs = threadIdx.x >> 5;  // 0..7
  int qbase = blockIdx.x * 32;
  double sx = 0, sxx = 0, sf = 0, sff = 0;
  for (int jj = 0; jj < 4; ++jj) {
    int q = qbase + qs * 4 + jj;
    int b = q / S;
    int nbr = knn[(size_t)q * 32 + k];
    int fq = fidx[q];
    const float* xr = x + ((size_t)b * N + nbr) * 3;
    const float* xq = xs + (size_t)q * 3;
#pragma unroll
    for (int c = 0; c < 3; ++c) {
      float d = xr[c] - xq[c];
      sx += (double)d;
      sxx += (double)d * (double)d;
    }
    const float4* fr = (const float4*)(feat + ((size_t)b * N + nbr) * C);
    const float4* fqv = (const float4*)(feat + ((size_t)b * N + fq) * C);
    for (int c = 0; c < C / 4; ++c) {
      float4 a = fr[c], bb = fqv[c];
      float d0 = a.x - bb.x, d1 = a.y - bb.y, d2 = a.z - bb.z, d3 = a.w - bb.w;
      sf += (double)d0 + (double)d1 + (double)d2 + (double)d3;
      sff += (double)d0 * d0 + (double)d1 * d1 + (double)d2 * d2 + (double)d3 * d3;
    }
  }
  __shared__ double red[256];
  double vals[4] = {sx, sxx, sf, sff};
  double rr[4] = {0, 0, 0, 0};
#pragma unroll
  for (int p = 0; p < 4; ++p) {
    red[threadIdx.x] = vals[p];
    __syncthreads();
    if (threadIdx.x < 32) {
      double r = 0;
#pragma unroll
      for (int t = 0; t < 8; ++t) r += red[k + t * 32];
      rr[p] = r;
    }
    __syncthreads();
  }
  if (threadIdx.x < 32) {
    atomicAdd(&acc_xk[k * 2 + 0], rr[0]);
    atomicAdd(&acc_xk[k * 2 + 1], rr[1]);
    atomicAdd(&acc_fk[k * 2 + 0], rr[2]);
    atomicAdd(&acc_fk[k * 2 + 1], rr[3]);
  }
}

__global__ void finish_std(const double* __restrict__ acc_xk, const double* __restrict__ acc_fk,
                           float* __restrict__ pstd, int n1, int n2) {
  int k = threadIdx.x;
  if (k < 32) {
    double s = acc_xk[k * 2], ss = acc_xk[k * 2 + 1];
    double var = (ss - s * s / (double)n1) / (double)(n1 - 1);
    float st = (float)sqrt(var > 0.0 ? var : 0.0);
    st = fmaxf(st, 1e-5f);
    pstd[k] = 1.0f / st;
    s = acc_fk[k * 2];
    ss = acc_fk[k * 2 + 1];
    var = (ss - s * s / (double)n2) / (double)(n2 - 1);
    st = (float)sqrt(var > 0.0 ? var : 0.0);
    st = fmaxf(st, 1e-5f);
    pstd[32 + k] = 1.0f / st;
  }
}

// ================= gstd stats over normalized xk =================
__global__ __launch_bounds__(256) void stats2_kernel(const float* __restrict__ x,
                                                     const float* __restrict__ xs,
                                                     const int* __restrict__ knn,
                                                     const float* __restrict__ pstd,
                                                     double* __restrict__ acc_g, int S, int N) {
  int b = blockIdx.y;
  int total = S * 32;
  double a[3] = {0, 0, 0}, qq[3] = {0, 0, 0};
  for (int u = blockIdx.x * 256 + threadIdx.x; u < total; u += 32 * 256) {
    int s = u >> 5, k = u & 31;
    int nbr = knn[((size_t)b * S + s) * 32 + k];
    float is = pstd[k];
#pragma unroll
    for (int c = 0; c < 3; ++c) {
      float v = (x[((size_t)b * N + nbr) * 3 + c] - xs[((size_t)b * S + s) * 3 + c]) * is;
      a[c] += (double)v;
      qq[c] += (double)v * (double)v;
    }
  }
  __shared__ double red[256];
#pragma unroll
  for (int c = 0; c < 3; ++c) {
    red[threadIdx.x] = a[c];
    __syncthreads();
    for (int off = 128; off > 0; off >>= 1) {
      if (threadIdx.x < off) red[threadIdx.x] += red[threadIdx.x + off];
      __syncthreads();
    }
    if (threadIdx.x == 0) atomicAdd(&acc_g[(b * 3 + c) * 2], red[0]);
    __syncthreads();
    red[threadIdx.x] = qq[c];
    __syncthreads();
    for (int off = 128; off > 0; off >>= 1) {
      if (threadIdx.x < off) red[threadIdx.x] += red[threadIdx.x + off];
      __syncthreads();
    }
    if (threadIdx.x == 0) atomicAdd(&acc_g[(b * 3 + c) * 2 + 1], red[0]);
    __syncthreads();
  }
}

// gstd (24 slots of n samples each) -> params {inv(asig+eps), blend};
// then zeroes the stage accumulators (176 dbl) for the NEXT stage's atomics.
// Safe ordering: this kernel runs after the current stage's stats1/stats2
// and before the next stage's stats1 (stream-serial).
__global__ void finish_gstd(const double* __restrict__ acc, float* __restrict__ params, int n,
                            double* __restrict__ accz) {
  if (threadIdx.x == 0) {
    double g = 0;
    for (int i = 0; i < 24; ++i) {
      double s = acc[i * 2], ss = acc[i * 2 + 1];
      double var = (ss - s * s / (double)n) / (double)(n - 1);
      g += sqrt(var > 0.0 ? var : 0.0);
    }
    float gstd = (float)(g / 24.0);
    float asig = 0.26f * (1.0f + gstd);
    params[0] = 1.0f / (asig + 1e-6f);
    params[1] = 1.0f / (1.0f + expf(-(gstd - 0.1f) * 10.0f));
  }
  __syncthreads();
  for (int i = threadIdx.x; i < 176; i += 64) accz[i] = 0.0;
}

// ================= init stats + init embed =================
__global__ __launch_bounds__(256) void init_stats(const float* __restrict__ xyz,
                                                  double* __restrict__ acc) {
  int bc = blockIdx.x;
  int b = bc / 3, c = bc - b * 3;
  double s = 0, ss = 0;
  for (int n = threadIdx.x; n < 4096; n += 256) {
    float v = xyz[((size_t)b * 4096 + n) * 3 + c];
    s += (double)v;
    ss += (double)v * (double)v;
  }
  __shared__ double r1[256], r2[256];
  r1[threadIdx.x] = s;
  r2[threadIdx.x] = ss;
  __syncthreads();
  for (int off = 128; off > 0; off >>= 1) {
    if (threadIdx.x < off) {
      r1[threadIdx.x] += r1[threadIdx.x + off];
      r2[threadIdx.x] += r2[threadIdx.x + off];
    }
    __syncthreads();
  }
  if (threadIdx.x == 0) {
    acc[bc * 2] = r1[0];
    acc[bc * 2 + 1] = r2[0];
  }
}

__global__ __launch_bounds__(256) void init_embed(const float* __restrict__ xyz,
                                                  const float* __restrict__ params,
                                                  float* __restrict__ feat) {
  int t = blockIdx.x * 256 + threadIdx.x;  // over 8*4096*64
  int j = t & 63;
  int n = (t >> 6) & 4095;
  int b = t >> 18;
  float inv_ae = params[0], blend = params[1];
  int idx = (int)((double)j * 65.0 / 63.0);
  int c = idx / 22, f = idx - c * 22;
  float fv = (float)(-1.0 + 2.0 * (double)(f + 1) / 23.0);
  float v = xyz[((size_t)b * 4096 + n) * 3 + c];
  float z = (v - fv) * inv_ae;
  float e = __expf(-0.5f * z * z);
  float co = __cosf(z);
  feat[t] = blend * e + (1.0f - blend) * co;
}

// ================= fused embed + gate + K-reduce + gelu =================
template <int C, int TWOC, int BLK, int FD>
__global__ __launch_bounds__(BLK) void fused_kernel(const float* __restrict__ x,
                                                    const float* __restrict__ xs,
                                                    const float* __restrict__ feat_in,
                                                    const int* __restrict__ fidx,
                                                    const int* __restrict__ knn,
                                                    const float* __restrict__ pstd,
                                                    float* __restrict__ feat_out, int S, int N) {
  constexpr int JPT = TWOC / BLK;
  int q = blockIdx.x;
  int b = q / S;
  int tid = threadIdx.x;
  float inv_ae = pstd[64];
  float blend = pstd[65];
  float omb = 1.0f - blend;
  float c0 = xs[(size_t)q * 3 + 0];
  float c1 = xs[(size_t)q * 3 + 1];
  float c2 = xs[(size_t)q * 3 + 2];
  const float* fsrow = feat_in + ((size_t)b * N + fidx[q]) * C;

  int cj[JPT];
  float fvj[JPT], fj[JPT], sum[JPT], mx[JPT];
#pragma unroll
  for (int i = 0; i < JPT; ++i) {
    int j = tid + i * BLK;
    int idx = (int)((double)j * (double)(3 * FD - 1) / (double)(TWOC - 1));
    int c = idx / FD, f = idx - c * FD;
    cj[i] = c;
    fvj[i] = (float)(-1.0 + 2.0 * (double)(f + 1) / (double)(FD + 1));
    fj[i] = fsrow[j < C ? j : j - C];
    sum[i] = 0.0f;
    mx[i] = -3.4e38f;
  }

  const int* krow = knn + (size_t)q * 32;
#pragma unroll 1
  for (int k = 0; k < 32; ++k) {
    int nbr = krow[k];
    float isx = pstd[k], isf = pstd[32 + k];
    const float* xr = x + ((size_t)b * N + nbr) * 3;
    float xk0 = (xr[0] - c0) * isx;
    float xk1 = (xr[1] - c1) * isx;
    float xk2 = (xr[2] - c2) * isx;
    const float* fr = feat_in + ((size_t)b * N + nbr) * C;
#pragma unroll
    for (int i = 0; i < JPT; ++i) {
      int j = tid + i * BLK;
      float cat;
      if (j < C)
        cat = (fr[j] - fj[i]) * isf;
      else
        cat = fj[i];
      float xc = (cj[i] == 0) ? xk0 : ((cj[i] == 1) ? xk1 : xk2);
      float z = (xc - fvj[i]) * inv_ae;
      float comb = blend * __expf(-0.5f * z * z) + omb * __cosf(z);
      float fw = (cat + comb) * comb;
      sum[i] += fw;
      mx[i] = fmaxf(mx[i], fw);
    }
  }
#pragma unroll
  for (int i = 0; i < JPT; ++i) {
    float val = sum[i] * 0.03125f + mx[i];
    float g = 0.5f * val * (1.0f + erff(val * 0.7071067811865476f));
    feat_out[(size_t)q * TWOC + tid + i * BLK] = g;
  }
}

// ================= stage result reduce (max & mean over S) =================
template <int TWOC, int BLK>
__global__ __launch_bounds__(BLK) void result_partial(const float* __restrict__ feat,
                                                      float* __restrict__ pmax,
                                                      double* __restrict__ psum, int S) {
  int j = blockIdx.x * BLK + threadIdx.x;
  int ch = blockIdx.y, b = blockIdx.z;
  int rows = S >> 3;
  int s0 = ch * rows;
  float m = -3.4e38f;
  double sd = 0.0;
  for (int s = 0; s < rows; ++s) {
    float v = feat[((size_t)(b * S + s0 + s)) * TWOC + j];
    m = fmaxf(m, v);
    sd += (double)v;
  }
  pmax[((size_t)ch * 8 + b) * TWOC + j] = m;
  psum[((size_t)ch * 8 + b) * TWOC + j] = sd;
}

__global__ void result_final(const float* __restrict__ pmax, const double* __restrict__ psum,
                             float* __restrict__ out, int TWOC, int off, int S) {
  int t = blockIdx.x * 256 + threadIdx.x;
  if (t >= 8 * TWOC) return;
  int b = t / TWOC, j = t - b * TWOC;
  float m = -3.4e38f;
  double sd = 0.0;
  for (int ch = 0; ch < 8; ++ch) {
    m = fmaxf(m, pmax[((size_t)ch * 8 + b) * TWOC + j]);
    sd += psum[((size_t)ch * 8 + b) * TWOC + j];
  }
  out[(size_t)b * 3840 + off + j] = m;
  out[(size_t)b * 3840 + off + TWOC + j] = (float)(sd / (double)S);
}

// ================= stage driver =================
template <int N, int S, int C, int TWOC, int FD, int FBLK, int FP, int KP, int BLKF>
static void run_stage(const float* x, const float* feat_in, float* xs, float* feat_out,
                      int* fps, int* knnb, double* accz, float* pstd, float* pmax, double* psum,
                      float* out, int outoff, hipStream_t stream) {
  static_assert(FBLK * FP == N, "fps size");
  static_assert(64 * KP == N, "knn size");
  double* acc_xk = accz;
  double* acc_fk = accz + 64;
  double* acc_g = accz + 128;

  fps_kernel<FBLK, FP><<<8, FBLK, 0, stream>>>(x, fps, S);
  gather_xs_kernel<<<(8 * S * 3 + 255) / 256, 256, 0, stream>>>(x, fps, xs, S, N);
  knn_kernel<KP><<<(8 * S) / 4, 256, 0, stream>>>(x, xs, knnb, S);
  stats1_kernel<C><<<(8 * S) / 32, 256, 0, stream>>>(x, xs, feat_in, fps, knnb, acc_xk, acc_fk, S, N);
  finish_std<<<1, 64, 0, stream>>>(acc_xk, acc_fk, pstd, 8 * S * 3, 8 * S * C);
  stats2_kernel<<<dim3(32, 8), 256, 0, stream>>>(x, xs, knnb, pstd, acc_g, S, N);
  finish_gstd<<<1, 64, 0, stream>>>(acc_g, pstd + 64, S * 32, accz);
  fused_kernel<C, TWOC, BLKF, FD><<<8 * S, BLKF, 0, stream>>>(x, xs, feat_in, fps, knnb, pstd,
                                                              feat_out, S, N);
  constexpr int RBLK = (TWOC < 256) ? TWOC : 256;
  result_partial<TWOC, RBLK><<<dim3(TWOC / RBLK, 8, 8), RBLK, 0, stream>>>(feat_out, pmax, psum, S);
  result_final<<<(8 * TWOC + 255) / 256, 256, 0, stream>>>(pmax, psum, out, TWOC, outoff, S);
}

extern "C" void kernel_launch(void* const* d_in, const int* in_sizes, int n_in, void* d_out,
                              int out_size, void* d_ws, size_t ws_size, hipStream_t stream) {
  (void)in_sizes;
  (void)n_in;
  (void)out_size;
  (void)ws_size;
  const float* xyz = (const float*)d_in[0];
  float* out = (float*)d_out;
  char* w = (char*)d_ws;

  float* featA = (float*)(w + WS_FEAT_A);
  float* featB = (float*)(w + WS_FEAT_B);
  float* xs0 = (float*)(w + WS_XS0);
  float* xs1 = (float*)(w + WS_XS1);
  int* fps = (int*)(w + WS_FPS);
  int* knnb = (int*)(w + WS_KNN);
  float* pmax = (float*)(w + WS_PMAX);
  double* psum = (double*)(w + WS_PSUM);
  double* accz = (double*)(w + WS_ACC);
  double* acci = (double*)(w + WS_ACCI);
  float* pstd = (float*)(w + WS_PSTD);
  float* pinit = (float*)(w + WS_PINIT);

  // initial adaptive embed of xyz -> feat [8,4096,64]; finish_gstd also
  // zeroes the per-stage accumulators (covers first launch + graph replay).
  init_stats<<<24, 256, 0, stream>>>(xyz, acci);
  finish_gstd<<<1, 64, 0, stream>>>(acci, pinit, 4096, accz);
  init_embed<<<(8 * 4096 * 64) / 256, 256, 0, stream>>>(xyz, pinit, featA);

  // 4 stages
  run_stage<4096, 2048, 64, 128, 43, 256, 16, 64, 128>(xyz, featA, xs0, featB, fps, knnb,
                                                       accz, pstd, pmax, psum, out, 0, stream);
  run_stage<2048, 1024, 128, 256, 86, 256, 8, 32, 256>(xs0, featB, xs1, featA, fps, knnb,
                                                       accz, pstd, pmax, psum, out, 256, stream);
  run_stage<1024, 512, 256, 512, 171, 64, 16, 16, 256>(xs1, featA, xs0, featB, fps, knnb,
                                                       accz, pstd, pmax, psum, out, 768, stream);
  run_stage<512, 256, 512, 1024, 342, 64, 8, 8, 256>(xs0, featB, xs1, featA, fps, knnb,
                                                     accz, pstd, pmax, psum, out, 1792, stream);
}